// Round 5
// baseline (702.625 us; speedup 1.0000x reference)
//
#include <hip/hip_runtime.h>

typedef unsigned int u32;
typedef unsigned short u16;
typedef short bf16x8 __attribute__((ext_vector_type(8)));   // 8 bf16 (4 VGPRs)
typedef float f32x4 __attribute__((ext_vector_type(4)));    // MFMA accumulator

__device__ __forceinline__ float bf2f(u16 h) { return __uint_as_float(((u32)h) << 16); }
__device__ __forceinline__ u16 f2bf(float f) {
    u32 u = __float_as_uint(f);
    return (u16)((u + 0x7fffu + ((u >> 16) & 1u)) >> 16);   // RNE
}

// ---------------- diagnostic fallback: ws too small ----------------
__global__ __launch_bounds__(256) void k_sentinel(u16* out, int n) {
    int i = blockIdx.x * 256 + threadIdx.x;
    if (i < n) out[i] = f2bf(-7.0f);
}

// ---------------- dtype detection: flag=0 bf16-packed, flag=1 f32 ----------------
__global__ void k_detect(const u32* x, int* flag) {
    int lane = threadIdx.x;  // 64 threads
    int c = 0;
    for (int j = 0; j < 4; ++j) {
        u32 u = x[lane * 4 + j];
        u32 e = (u >> 7) & 0xffu;
        if ((e >= 0x30u && e <= 0x47u) || ((u & 0x7fffu) == 0u)) ++c;
    }
    for (int d = 32; d; d >>= 1) c += __shfl_down(c, d, 64);
    if (lane == 0) *flag = (c < 128) ? 1 : 0;
}

// ---------------- converters into canonical packed-bf16 / f32 ----------------
__global__ __launch_bounds__(256) void k_cvt(const void* src, const int* flag,
                                             u32* dst, int n) {  // n = u32 words out
    int i = blockIdx.x * 256 + threadIdx.x;
    if (i >= n) return;
    if (*flag) {
        const float* s = (const float*)src;
        dst[i] = (u32)f2bf(s[2 * i]) | ((u32)f2bf(s[2 * i + 1]) << 16);
    } else {
        dst[i] = ((const u32*)src)[i];
    }
}

// fused parameter conversion: 4 big weights (32 blocks each), 2 small (2 each), biases
__global__ __launch_bounds__(256) void k_cvtp(
    const void* s1l, const void* s1r, const void* shl, const void* shr,
    const void* s2l, const void* s2r, const void* sb1, const void* sbh,
    const void* sb2, const int* flag,
    u32* w1l, u32* w1r, u32* whl, u32* whr, u32* w2l, u32* w2r,
    float* bf1, float* bfh, float* bf2) {
    int b = blockIdx.x, t = threadIdx.x;
    int fl = *flag;
    auto cv = [&](const void* src, u32* dst, int base) {
        int i = base + t;
        if (fl) {
            const float* s = (const float*)src;
            dst[i] = (u32)f2bf(s[2 * i]) | ((u32)f2bf(s[2 * i + 1]) << 16);
        } else {
            dst[i] = ((const u32*)src)[i];
        }
    };
    auto cb = [&](const void* src, float* dst, int i) {
        dst[i] = fl ? ((const float*)src)[i] : bf2f(((const u16*)src)[i]);
    };
    if      (b <  32) cv(s1l, w1l, b * 256);
    else if (b <  64) cv(s1r, w1r, (b - 32) * 256);
    else if (b <  96) cv(shl, whl, (b - 64) * 256);
    else if (b < 128) cv(shr, whr, (b - 96) * 256);
    else if (b < 130) cv(s2l, w2l, (b - 128) * 256);
    else if (b < 132) cv(s2r, w2r, (b - 130) * 256);
    else if (b == 132) {
        if (t < 128) cb(sb1, bf1, t);
        else         cb(sbh, bfh, t - 128);
    } else {
        if (t < 8) cb(sb2, bf2, t);
    }
}

// ---------------- CSR build ----------------
// per-node degree + per-bucket (dst>>6) histogram in one pass
__global__ __launch_bounds__(256) void k_hist(const int* dstv, int* deg, int* bcnt,
                                              int E, int N) {
    int e = blockIdx.x * 256 + threadIdx.x;
    if (e >= E) return;
    int d = dstv[e]; d = min(max(d, 0), N - 1);
    atomicAdd(&deg[d], 1);
    atomicAdd(&bcnt[d >> 6], 1);
}

__global__ __launch_bounds__(512) void k_scan1(const int* deg, int* rowptr,
                                               int* bsums, int N) {
    __shared__ int sm[512];
    int i = blockIdx.x * 512 + threadIdx.x;
    int v = (i < N) ? deg[i] : 0;
    sm[threadIdx.x] = v;
    __syncthreads();
    for (int off = 1; off < 512; off <<= 1) {
        int t = (threadIdx.x >= off) ? sm[threadIdx.x - off] : 0;
        __syncthreads();
        sm[threadIdx.x] += t;
        __syncthreads();
    }
    if (i < N) rowptr[i] = sm[threadIdx.x] - v;            // exclusive
    if (threadIdx.x == 511) bsums[blockIdx.x] = sm[511];
}

__global__ __launch_bounds__(128) void k_scan2(int* bsums, int nb) {
    __shared__ int sm[128];
    int v = (threadIdx.x < nb) ? bsums[threadIdx.x] : 0;
    sm[threadIdx.x] = v;
    __syncthreads();
    for (int off = 1; off < 128; off <<= 1) {
        int t = (threadIdx.x >= off) ? sm[threadIdx.x - off] : 0;
        __syncthreads();
        sm[threadIdx.x] += t;
        __syncthreads();
    }
    if (threadIdx.x < nb) bsums[threadIdx.x] = sm[threadIdx.x] - v;  // exclusive
}

__global__ __launch_bounds__(512) void k_scan3(int* rowptr, const int* bsums,
                                               int N, int E) {
    int i = blockIdx.x * 512 + threadIdx.x;
    if (i < N) rowptr[i] += bsums[blockIdx.x];
    if (i == 0) rowptr[N] = E;
}

// exclusive scan of bucket counts (nb <= 1024), one block
__global__ __launch_bounds__(1024) void k_scanb(const int* bcnt, int* boff, int nb) {
    __shared__ int sm[1024];
    int i = threadIdx.x;
    int v = (i < nb) ? bcnt[i] : 0;
    sm[i] = v;
    __syncthreads();
    for (int off = 1; off < 1024; off <<= 1) {
        int t = (i >= off) ? sm[i - off] : 0;
        __syncthreads();
        sm[i] += t;
        __syncthreads();
    }
    if (i < nb) boff[i] = sm[i] - v;
}

// append edges into bucket-segmented pairs; boff mutates to bucket ENDS
__global__ __launch_bounds__(256) void k_scatter(const int* srcv, const int* dstv,
                                                 int* boff, u32* pairs, int E, int N) {
    int e = blockIdx.x * 256 + threadIdx.x;
    if (e >= E) return;
    int s = min(max(srcv[e], 0), N - 1);
    int d = min(max(dstv[e], 0), N - 1);
    int pos = atomicAdd(&boff[d >> 6], 1);
    pos = min(max(pos, 0), E - 1);
    pairs[pos] = ((u32)s << 16) | (u32)d;   // requires N <= 65536 (host-guarded)
}

// one workgroup per bucket: LDS cursors, XCD-exclusive 4KB adj window
__global__ __launch_bounds__(256) void k_fill2(const u32* pairs, const int* boff,
                                               const int* rowptr, const int* deg,
                                               int* adj, int E, int N) {
    int w = blockIdx.x;
    int n0 = w << 6;
    __shared__ int lcur[64];
    if (threadIdx.x < 64) {
        int n = n0 + threadIdx.x;
        lcur[threadIdx.x] = (n < N) ? deg[n] : 0;
    }
    __syncthreads();
    int start = (w == 0) ? 0 : boff[w - 1];   // post-scatter: boff[w] = end of bucket w
    int end = boff[w];
    start = min(max(start, 0), E);
    end = min(max(end, start), E);
    for (int e = start + threadIdx.x; e < end; e += 256) {
        u32 pc = pairs[e];
        int d = (int)(pc & 0xffffu);
        int s = (int)(pc >> 16);
        int local = min(max(d - n0, 0), 63);
        int slot = atomicSub(&lcur[local], 1) - 1;
        int idx = rowptr[d] + slot;
        idx = min(max(idx, 0), E - 1);
        adj[idx] = s;
    }
}

// fallback for N > 65536: direct scatter (destroys deg as countdown cursor)
__global__ __launch_bounds__(256) void k_fill(const int* srcv, const int* dstv,
                                              const int* rowptr, int* deg,
                                              int* adj, int E, int N) {
    int e = blockIdx.x * 256 + threadIdx.x;
    if (e >= E) return;
    int d = dstv[e]; d = min(max(d, 0), N - 1);
    int slot = atomicSub(&deg[d], 1) - 1;
    int idx = rowptr[d] + slot;
    idx = min(max(idx, 0), E - 1);
    adj[idx] = srcv[e];
}

// ---------------- mean aggregation: one wave per node, 4x16-lane groups, unroll 4 --
// 16 independent 16B loads in flight per wave; a degree-16 node = 1 unrolled iter.
__device__ __forceinline__ void acc8(uint4 u, float* s) {
    const u32* pu = (const u32*)&u;
#pragma unroll
    for (int t = 0; t < 4; ++t) {
        s[2 * t]     += __uint_as_float(pu[t] << 16);
        s[2 * t + 1] += __uint_as_float(pu[t] & 0xffff0000u);
    }
}

__global__ __launch_bounds__(256) void k_aggregate(const uint4* F, const int* rowptr,
                                                   const int* adj, uint4* A,
                                                   int N, int E) {
    int wid = (int)((blockIdx.x * 256u + threadIdx.x) >> 6);
    int lane = threadIdx.x & 63;
    if (wid >= N) return;
    int beg = rowptr[wid], end = rowptr[wid + 1];
    beg = min(max(beg, 0), E);
    end = min(max(end, beg), E);
    int g = lane >> 4, l = lane & 15;
    float s[8] = {0.f, 0.f, 0.f, 0.f, 0.f, 0.f, 0.f, 0.f};
    int j = beg + g;
    for (; j + 12 < end; j += 16) {
        int a0 = min(max(adj[j], 0), N - 1);
        int a1 = min(max(adj[j + 4], 0), N - 1);
        int a2 = min(max(adj[j + 8], 0), N - 1);
        int a3 = min(max(adj[j + 12], 0), N - 1);
        uint4 u0 = F[(size_t)a0 * 16 + l];
        uint4 u1 = F[(size_t)a1 * 16 + l];
        uint4 u2 = F[(size_t)a2 * 16 + l];
        uint4 u3 = F[(size_t)a3 * 16 + l];
        acc8(u0, s); acc8(u1, s); acc8(u2, s); acc8(u3, s);
    }
    for (; j < end; j += 4) {
        int a0 = min(max(adj[j], 0), N - 1);
        uint4 u0 = F[(size_t)a0 * 16 + l];
        acc8(u0, s);
    }
#pragma unroll
    for (int k = 0; k < 8; ++k) {
        s[k] += __shfl_xor(s[k], 16, 64);
        s[k] += __shfl_xor(s[k], 32, 64);
    }
    if (g == 0) {
        float inv = 1.f / fmaxf((float)(end - beg), 1.f);
        uint4 r; u32* pr = (u32*)&r;
#pragma unroll
        for (int t = 0; t < 4; ++t)
            pr[t] = (u32)f2bf(s[2 * t] * inv) | ((u32)f2bf(s[2 * t + 1] * inv) << 16);
        A[(size_t)wid * 16 + l] = r;
    }
}

// ---------------- fused SAGE GEMM: h = act(Agg@Wl^T + b + Xin@Wr^T) ----------------
// One wave per 16-node tile; K=256 (agg||x vs Wl||Wr), 8 col-tiles.
// Each wave reads only its own 16 rows fully into regs before storing those same
// rows -> Out may alias Agg or Xin. (No __restrict__: aliasing is intentional.)
template <int ACT>  // 0 = relu, 1 = elu
__global__ __launch_bounds__(256) void k_gemm128(const u16* Agg, const u16* Xin,
                                                 const u32* Wl, const u32* Wr,
                                                 const float* bias, u16* Out, int N) {
    int tile = blockIdx.x * 4 + (threadIdx.x >> 6);
    int lane = threadIdx.x & 63;
    int m0 = tile * 16;
    if (m0 >= N) return;
    int mrow = m0 + (lane & 15);
    int kq = (lane >> 4) * 8;

    bf16x8 afrag[8];
#pragma unroll
    for (int s = 0; s < 8; ++s) {
        int k = s * 32 + kq;
        const u16* p = (k < 128) ? (Agg + (size_t)mrow * 128 + k)
                                 : (Xin + (size_t)mrow * 128 + (k - 128));
        afrag[s] = *(const bf16x8*)p;
    }

    f32x4 acc[8];
#pragma unroll
    for (int c = 0; c < 8; ++c) acc[c] = (f32x4){0.f, 0.f, 0.f, 0.f};

#pragma unroll
    for (int c = 0; c < 8; ++c) {
        int o = c * 16 + (lane & 15);
#pragma unroll
        for (int s = 0; s < 8; ++s) {
            int k = s * 32 + kq;
            const u32* p = (k < 128) ? (Wl + ((size_t)o * 128 + k) / 2)
                                     : (Wr + ((size_t)o * 128 + (k - 128)) / 2);
            bf16x8 b = *(const bf16x8*)p;
            acc[c] = __builtin_amdgcn_mfma_f32_16x16x32_bf16(afrag[s], b, acc[c], 0, 0, 0);
        }
    }

#pragma unroll
    for (int c = 0; c < 8; ++c) {
        int o = c * 16 + (lane & 15);
        float bv = bias[o];
#pragma unroll
        for (int r = 0; r < 4; ++r) {
            int m = m0 + (lane >> 4) * 4 + r;
            float v = acc[c][r] + bv;
            v = (ACT == 0) ? fmaxf(v, 0.f) : ((v > 0.f) ? v : expm1f(v));
            Out[(size_t)m * 128 + o] = f2bf(v);
        }
    }
}

// ---------------- layer 3: y = h2@W2l^T, r = h2@W2r^T + b  (both [N,8] f32) -------
__device__ __forceinline__ float dot8(uint4 a, uint4 b, float acc) {
    const u32* pa = (const u32*)&a;
    const u32* pb = (const u32*)&b;
#pragma unroll
    for (int t = 0; t < 4; ++t) {
        acc = fmaf(__uint_as_float(pa[t] << 16), __uint_as_float(pb[t] << 16), acc);
        acc = fmaf(__uint_as_float(pa[t] & 0xffff0000u),
                   __uint_as_float(pb[t] & 0xffff0000u), acc);
    }
    return acc;
}

__global__ __launch_bounds__(256) void k_lin8(const u16* Xin, const u32* Wl,
                                              const u32* Wr, const float* bias,
                                              float* Y, float* R, int N) {
    int t = blockIdx.x * 256 + threadIdx.x;
    int n = t >> 3;
    int o = t & 7;
    if (n >= N) return;
    const uint4* xr = (const uint4*)(Xin + (size_t)n * 128);
    const uint4* wl = (const uint4*)(Wl + (size_t)o * 64);
    const uint4* wr = (const uint4*)(Wr + (size_t)o * 64);
    float al = 0.f, ar = bias[o];
#pragma unroll
    for (int i = 0; i < 16; ++i) {
        uint4 xv = xr[i];
        al = dot8(xv, wl[i], al);
        ar = dot8(xv, wr[i], ar);
    }
    Y[(size_t)n * 8 + o] = al;
    R[(size_t)n * 8 + o] = ar;
}

// mean-aggregate Y (f32 [N,8], 1.6 MB -> L2-resident) + r + log_softmax.
__global__ __launch_bounds__(256) void k_agg8sm(const float* Y, const float* R,
                                                const int* rowptr, const int* adj,
                                                const int* flag, void* Out,
                                                int N, int E) {
    int t = blockIdx.x * 256 + threadIdx.x;
    int n = t >> 3;
    int o = t & 7;
    if (n >= N) return;
    int beg = rowptr[n], end = rowptr[n + 1];
    beg = min(max(beg, 0), E);
    end = min(max(end, beg), E);
    float s = 0.f;
    int j = beg;
    for (; j + 1 < end; j += 2) {
        int a0 = min(max(adj[j], 0), N - 1);
        int a1 = min(max(adj[j + 1], 0), N - 1);
        s += Y[(size_t)a0 * 8 + o];
        s += Y[(size_t)a1 * 8 + o];
    }
    if (j < end) {
        int a0 = min(max(adj[j], 0), N - 1);
        s += Y[(size_t)a0 * 8 + o];
    }
    float acc = s / fmaxf((float)(end - beg), 1.f) + R[(size_t)n * 8 + o];
    float mx = acc;
#pragma unroll
    for (int d = 1; d < 8; d <<= 1) mx = fmaxf(mx, __shfl_xor(mx, d, 64));
    float ex = expf(acc - mx), se = ex;
#pragma unroll
    for (int d = 1; d < 8; d <<= 1) se += __shfl_xor(se, d, 64);
    float v = acc - mx - logf(se);
    if (*flag) ((float*)Out)[(size_t)n * 8 + o] = v;
    else       ((u16*)Out)[(size_t)n * 8 + o] = f2bf(v);
}

// ---------------- launch ----------------
extern "C" void kernel_launch(void* const* d_in, const int* in_sizes, int n_in,
                              void* d_out, int out_size, void* d_ws, size_t ws_size,
                              hipStream_t stream) {
    const void* x   = d_in[0];
    const int* ei   = (const int*)d_in[1];
    const int N = in_sizes[0] / 128;
    const int E = in_sizes[1] / 2;
    const int* srcv = ei;
    const int* dstv = ei + E;
    const int NB = (N + 63) >> 6;            // buckets of 64 nodes
    const bool bucketed = (N <= 65536);      // packed u32 pairs need 16-bit ids

    auto rnd = [](size_t b) { return (b + 255) & ~(size_t)255; };
    size_t need = rnd(256)                    // flag
                + rnd((size_t)N * 4)          // deg
                + rnd((size_t)NB * 4)         // bcnt (adjacent to deg: one memset)
                + rnd((size_t)(N + 1) * 4)    // rowptr
                + rnd(4096)                   // bsums
                + rnd((size_t)NB * 4)         // boff
                + rnd((size_t)E * 4)          // adj
                + 2 * rnd((size_t)N * 256)    // X, A (packed bf16 [N,128])
                + 4 * rnd(32768) + 2 * rnd(2048) + 2 * rnd(512) + rnd(64);
    if (ws_size < need) {
        k_sentinel<<<(out_size + 255) / 256, 256, 0, stream>>>((u16*)d_out, out_size);
        return;
    }

    char* p = (char*)d_ws;
    auto carve = [&](size_t bytes) { char* r = p; p += (bytes + 255) & ~(size_t)255; return r; };
    int* flag   = (int*)carve(256);
    int* deg    = (int*)carve((size_t)N * 4);
    int* bcnt   = (int*)carve((size_t)NB * 4);   // contiguous after deg
    int* rowptr = (int*)carve((size_t)(N + 1) * 4);
    int* bsums  = (int*)carve(4096);
    int* boff   = (int*)carve((size_t)NB * 4);
    int* adj    = (int*)carve((size_t)E * 4);
    u32* X      = (u32*)carve((size_t)N * 256);   // [N,128] packed bf16
    u32* A      = (u32*)carve((size_t)N * 256);   // agg buffer; dead until 1st aggregate
    u32* w1l = (u32*)carve(32768); u32* w1r = (u32*)carve(32768);
    u32* whl = (u32*)carve(32768); u32* whr = (u32*)carve(32768);
    u32* w2l = (u32*)carve(2048);  u32* w2r = (u32*)carve(2048);
    float* bf1 = (float*)carve(512); float* bfh = (float*)carve(512);
    float* bf2 = (float*)carve(64);
    // pairs (E u32 = 3.2 MB) aliases A: fully consumed by k_fill2 before aggregate
    u32* pairs = A;
    // layer-3 Y/R ([N,8] f32 = 1.6 MB each) also live in dead A
    float* Y = (float*)A;
    float* R = Y + (size_t)N * 8;
    (void)n_in;

    k_detect<<<1, 64, 0, stream>>>((const u32*)x, flag);

    // canonicalize inputs
    k_cvt<<<(N * 64 + 255) / 256, 256, 0, stream>>>(x, flag, X, N * 64);
    k_cvtp<<<134, 256, 0, stream>>>(d_in[3], d_in[5], d_in[6], d_in[8], d_in[9],
                                    d_in[11], d_in[4], d_in[7], d_in[10], flag,
                                    w1l, w1r, whl, whr, w2l, w2r, bf1, bfh, bf2);

    // CSR build
    hipMemsetAsync(deg, 0, rnd((size_t)N * 4) + rnd((size_t)NB * 4), stream);  // deg+bcnt
    int nb = (N + 511) / 512;
    k_hist<<<(E + 255) / 256, 256, 0, stream>>>(dstv, deg, bcnt, E, N);
    k_scan1<<<nb, 512, 0, stream>>>(deg, rowptr, bsums, N);
    k_scan2<<<1, 128, 0, stream>>>(bsums, nb);
    k_scan3<<<nb, 512, 0, stream>>>(rowptr, bsums, N, E);
    if (bucketed) {
        k_scanb<<<1, 1024, 0, stream>>>(bcnt, boff, NB);
        k_scatter<<<(E + 255) / 256, 256, 0, stream>>>(srcv, dstv, boff, pairs, E, N);
        k_fill2<<<NB, 256, 0, stream>>>(pairs, boff, rowptr, deg, adj, E, N);
    } else {
        k_fill<<<(E + 255) / 256, 256, 0, stream>>>(srcv, dstv, rowptr, deg, adj, E, N);
    }

    int aggBlocks = (int)(((size_t)N * 64 + 255) / 256);
    int gemmBlocks = ((N + 15) / 16 + 3) / 4;
    int perNode8 = (int)(((size_t)N * 8 + 255) / 256);

    // L1: A=mean(X); h1=relu(A@W1l^T+b1+X@W1r^T) -> X (own-rows aliasing, safe)
    k_aggregate<<<aggBlocks, 256, 0, stream>>>((const uint4*)X, rowptr, adj, (uint4*)A, N, E);
    k_gemm128<0><<<gemmBlocks, 256, 0, stream>>>((const u16*)A, (const u16*)X, w1l, w1r, bf1, (u16*)X, N);
    // L2: A=mean(h1=X); h2=elu(A@Whl^T+bh+X@Whr^T) -> X
    k_aggregate<<<aggBlocks, 256, 0, stream>>>((const uint4*)X, rowptr, adj, (uint4*)A, N, E);
    k_gemm128<1><<<gemmBlocks, 256, 0, stream>>>((const u16*)A, (const u16*)X, whl, whr, bfh, (u16*)X, N);
    // L3 (linearity): y=h2@W2l^T, r=h2@W2r^T+b2; out = log_softmax(mean_agg(y)+r)
    k_lin8<<<perNode8, 256, 0, stream>>>((const u16*)X, w2l, w2r, bf2, Y, R, N);
    k_agg8sm<<<perNode8, 256, 0, stream>>>(Y, R, rowptr, adj, flag, d_out, N, E);
}

// Round 6
// 366.764 us; speedup vs baseline: 1.9157x; 1.9157x over previous
//
#include <hip/hip_runtime.h>

typedef unsigned int u32;
typedef unsigned short u16;
typedef short bf16x8 __attribute__((ext_vector_type(8)));   // 8 bf16 (4 VGPRs)
typedef float f32x4 __attribute__((ext_vector_type(4)));    // MFMA accumulator

__device__ __forceinline__ float bf2f(u16 h) { return __uint_as_float(((u32)h) << 16); }
__device__ __forceinline__ u16 f2bf(float f) {
    u32 u = __float_as_uint(f);
    return (u16)((u + 0x7fffu + ((u >> 16) & 1u)) >> 16);   // RNE
}

// ---------------- diagnostic fallback: ws too small ----------------
__global__ __launch_bounds__(256) void k_sentinel(u16* out, int n) {
    int i = blockIdx.x * 256 + threadIdx.x;
    if (i < n) out[i] = f2bf(-7.0f);
}

// ---------------- dtype detection: flag=0 bf16-packed, flag=1 f32 ----------------
__global__ void k_detect(const u32* x, int* flag) {
    int lane = threadIdx.x;  // 64 threads
    int c = 0;
    for (int j = 0; j < 4; ++j) {
        u32 u = x[lane * 4 + j];
        u32 e = (u >> 7) & 0xffu;
        if ((e >= 0x30u && e <= 0x47u) || ((u & 0x7fffu) == 0u)) ++c;
    }
    for (int d = 32; d; d >>= 1) c += __shfl_down(c, d, 64);
    if (lane == 0) *flag = (c < 128) ? 1 : 0;
}

// ---------------- converters into canonical packed-bf16 / f32 ----------------
__global__ __launch_bounds__(256) void k_cvt(const void* src, const int* flag,
                                             u32* dst, int n) {  // n = u32 words out
    int i = blockIdx.x * 256 + threadIdx.x;
    if (i >= n) return;
    if (*flag) {
        const float* s = (const float*)src;
        dst[i] = (u32)f2bf(s[2 * i]) | ((u32)f2bf(s[2 * i + 1]) << 16);
    } else {
        dst[i] = ((const u32*)src)[i];
    }
}

// fused parameter conversion
__global__ __launch_bounds__(256) void k_cvtp(
    const void* s1l, const void* s1r, const void* shl, const void* shr,
    const void* s2l, const void* s2r, const void* sb1, const void* sbh,
    const void* sb2, const int* flag,
    u32* w1l, u32* w1r, u32* whl, u32* whr, u32* w2l, u32* w2r,
    float* bf1, float* bfh, float* bf2) {
    int b = blockIdx.x, t = threadIdx.x;
    int fl = *flag;
    auto cv = [&](const void* src, u32* dst, int base) {
        int i = base + t;
        if (fl) {
            const float* s = (const float*)src;
            dst[i] = (u32)f2bf(s[2 * i]) | ((u32)f2bf(s[2 * i + 1]) << 16);
        } else {
            dst[i] = ((const u32*)src)[i];
        }
    };
    auto cb = [&](const void* src, float* dst, int i) {
        dst[i] = fl ? ((const float*)src)[i] : bf2f(((const u16*)src)[i]);
    };
    if      (b <  32) cv(s1l, w1l, b * 256);
    else if (b <  64) cv(s1r, w1r, (b - 32) * 256);
    else if (b <  96) cv(shl, whl, (b - 64) * 256);
    else if (b < 128) cv(shr, whr, (b - 96) * 256);
    else if (b < 130) cv(s2l, w2l, (b - 128) * 256);
    else if (b < 132) cv(s2r, w2r, (b - 130) * 256);
    else if (b == 132) {
        if (t < 128) cb(sb1, bf1, t);
        else         cb(sbh, bfh, t - 128);
    } else {
        if (t < 8) cb(sb2, bf2, t);
    }
}

// ---------------- CSR build ----------------
// degree count: 800K atomics over 50K addresses (~16/addr: low contention, proven)
__global__ __launch_bounds__(256) void k_deg(const int* dstv, int* deg, int E, int N) {
    int e = blockIdx.x * 256 + threadIdx.x;
    if (e >= E) return;
    int d = dstv[e]; d = min(max(d, 0), N - 1);
    atomicAdd(&deg[d], 1);
}

__global__ __launch_bounds__(512) void k_scan1(const int* deg, int* rowptr,
                                               int* bsums, int N) {
    __shared__ int sm[512];
    int i = blockIdx.x * 512 + threadIdx.x;
    int v = (i < N) ? deg[i] : 0;
    sm[threadIdx.x] = v;
    __syncthreads();
    for (int off = 1; off < 512; off <<= 1) {
        int t = (threadIdx.x >= off) ? sm[threadIdx.x - off] : 0;
        __syncthreads();
        sm[threadIdx.x] += t;
        __syncthreads();
    }
    if (i < N) rowptr[i] = sm[threadIdx.x] - v;            // exclusive
    if (threadIdx.x == 511) bsums[blockIdx.x] = sm[511];
}

__global__ __launch_bounds__(128) void k_scan2(int* bsums, int nb) {
    __shared__ int sm[128];
    int v = (threadIdx.x < nb) ? bsums[threadIdx.x] : 0;
    sm[threadIdx.x] = v;
    __syncthreads();
    for (int off = 1; off < 128; off <<= 1) {
        int t = (threadIdx.x >= off) ? sm[threadIdx.x - off] : 0;
        __syncthreads();
        sm[threadIdx.x] += t;
        __syncthreads();
    }
    if (threadIdx.x < nb) bsums[threadIdx.x] = sm[threadIdx.x] - v;  // exclusive
}

// finalize rowptr; sample bucket cursors gcur[b] = rowptr[256*b]
__global__ __launch_bounds__(512) void k_scan3(int* rowptr, const int* bsums,
                                               int* gcur, int N, int E) {
    int i = blockIdx.x * 512 + threadIdx.x;
    if (i < N) {
        int v = rowptr[i] + bsums[blockIdx.x];
        rowptr[i] = v;
        if ((i & 255) == 0) gcur[i >> 8] = v;
    }
    if (i == 0) rowptr[N] = E;
}

// ---- bucketed fill, contention-bounded ----
// Phase A: 49 blocks x 16K-edge chunks. LDS histogram over <=256 buckets (256 nodes
// each), ONE global atomicAdd per (block,bucket) -> chain <= #blocks per address.
// Pass 2 appends (src<<8|local_d) into the block's reserved dense runs of pairs.
#define EB_CHUNK 16384
__global__ __launch_bounds__(256) void k_bucket(const int* srcv, const int* dstv,
                                                int* gcur, u32* pairs,
                                                int E, int N, int nbuk) {
    __shared__ int hist[256], base[256], cnt[256];
    int t = threadIdx.x;
    hist[t] = 0; cnt[t] = 0;
    __syncthreads();
    int e0 = blockIdx.x * EB_CHUNK;
    int e1 = min(e0 + EB_CHUNK, E);
    for (int e = e0 + t; e < e1; e += 256) {
        int d = min(max(dstv[e], 0), N - 1);
        atomicAdd(&hist[d >> 8], 1);
    }
    __syncthreads();
    if (t < nbuk && hist[t] > 0) base[t] = atomicAdd(&gcur[t], hist[t]);
    __syncthreads();
    for (int e = e0 + t; e < e1; e += 256) {
        int d = min(max(dstv[e], 0), N - 1);
        int s = min(max(srcv[e], 0), N - 1);
        int b = d >> 8;
        int pos = base[b] + atomicAdd(&cnt[b], 1);
        pos = min(max(pos, 0), E - 1);
        pairs[pos] = ((u32)s << 8) | (u32)(d & 255);   // N <= 65536 (host-guarded)
    }
}

// Phase B: one block per bucket; LDS countdown cursors; adj writes confined to the
// bucket's ~16KB XCD-exclusive window -> each 64B line absorbs ~16 writes.
__global__ __launch_bounds__(256) void k_fillb(const u32* pairs, const int* rowptr,
                                               const int* deg, int* adj, int E, int N) {
    int b = blockIdx.x;
    int n0 = b << 8;
    int nn = min(N - n0, 256);
    __shared__ int cur[256];
    int t = threadIdx.x;
    if (t < nn) cur[t] = deg[n0 + t];
    __syncthreads();
    int s0 = rowptr[n0];
    int s1 = rowptr[min(n0 + 256, N)];
    s0 = min(max(s0, 0), E);
    s1 = min(max(s1, s0), E);
    for (int e = s0 + t; e < s1; e += 256) {
        u32 pc = pairs[e];
        int ld = (int)(pc & 255u);
        ld = min(ld, nn - 1);
        int src = (int)(pc >> 8);
        int slot = atomicSub(&cur[ld], 1) - 1;
        int idx = rowptr[n0 + ld] + slot;
        idx = min(max(idx, 0), E - 1);
        adj[idx] = src;
    }
}

// fallback for N > 65536: direct scatter (destroys deg as countdown cursor)
__global__ __launch_bounds__(256) void k_fill(const int* srcv, const int* dstv,
                                              const int* rowptr, int* deg,
                                              int* adj, int E, int N) {
    int e = blockIdx.x * 256 + threadIdx.x;
    if (e >= E) return;
    int d = dstv[e]; d = min(max(d, 0), N - 1);
    int slot = atomicSub(&deg[d], 1) - 1;
    int idx = rowptr[d] + slot;
    idx = min(max(idx, 0), E - 1);
    adj[idx] = srcv[e];
}

// ---------------- mean aggregation: one wave per node, 4x16-lane groups, unroll 4 --
__device__ __forceinline__ void acc8(uint4 u, float* s) {
    const u32* pu = (const u32*)&u;
#pragma unroll
    for (int t = 0; t < 4; ++t) {
        s[2 * t]     += __uint_as_float(pu[t] << 16);
        s[2 * t + 1] += __uint_as_float(pu[t] & 0xffff0000u);
    }
}

__global__ __launch_bounds__(256) void k_aggregate(const uint4* F, const int* rowptr,
                                                   const int* adj, uint4* A,
                                                   int N, int E) {
    int wid = (int)((blockIdx.x * 256u + threadIdx.x) >> 6);
    int lane = threadIdx.x & 63;
    if (wid >= N) return;
    int beg = rowptr[wid], end = rowptr[wid + 1];
    beg = min(max(beg, 0), E);
    end = min(max(end, beg), E);
    int g = lane >> 4, l = lane & 15;
    float s[8] = {0.f, 0.f, 0.f, 0.f, 0.f, 0.f, 0.f, 0.f};
    int j = beg + g;
    for (; j + 12 < end; j += 16) {
        int a0 = min(max(adj[j], 0), N - 1);
        int a1 = min(max(adj[j + 4], 0), N - 1);
        int a2 = min(max(adj[j + 8], 0), N - 1);
        int a3 = min(max(adj[j + 12], 0), N - 1);
        uint4 u0 = F[(size_t)a0 * 16 + l];
        uint4 u1 = F[(size_t)a1 * 16 + l];
        uint4 u2 = F[(size_t)a2 * 16 + l];
        uint4 u3 = F[(size_t)a3 * 16 + l];
        acc8(u0, s); acc8(u1, s); acc8(u2, s); acc8(u3, s);
    }
    for (; j < end; j += 4) {
        int a0 = min(max(adj[j], 0), N - 1);
        uint4 u0 = F[(size_t)a0 * 16 + l];
        acc8(u0, s);
    }
#pragma unroll
    for (int k = 0; k < 8; ++k) {
        s[k] += __shfl_xor(s[k], 16, 64);
        s[k] += __shfl_xor(s[k], 32, 64);
    }
    if (g == 0) {
        float inv = 1.f / fmaxf((float)(end - beg), 1.f);
        uint4 r; u32* pr = (u32*)&r;
#pragma unroll
        for (int t = 0; t < 4; ++t)
            pr[t] = (u32)f2bf(s[2 * t] * inv) | ((u32)f2bf(s[2 * t + 1] * inv) << 16);
        A[(size_t)wid * 16 + l] = r;
    }
}

// ---------------- fused SAGE GEMM: h = act(Agg@Wl^T + b + Xin@Wr^T) ----------------
template <int ACT>  // 0 = relu, 1 = elu
__global__ __launch_bounds__(256) void k_gemm128(const u16* Agg, const u16* Xin,
                                                 const u32* Wl, const u32* Wr,
                                                 const float* bias, u16* Out, int N) {
    int tile = blockIdx.x * 4 + (threadIdx.x >> 6);
    int lane = threadIdx.x & 63;
    int m0 = tile * 16;
    if (m0 >= N) return;
    int mrow = m0 + (lane & 15);
    int kq = (lane >> 4) * 8;

    bf16x8 afrag[8];
#pragma unroll
    for (int s = 0; s < 8; ++s) {
        int k = s * 32 + kq;
        const u16* p = (k < 128) ? (Agg + (size_t)mrow * 128 + k)
                                 : (Xin + (size_t)mrow * 128 + (k - 128));
        afrag[s] = *(const bf16x8*)p;
    }

    f32x4 acc[8];
#pragma unroll
    for (int c = 0; c < 8; ++c) acc[c] = (f32x4){0.f, 0.f, 0.f, 0.f};

#pragma unroll
    for (int c = 0; c < 8; ++c) {
        int o = c * 16 + (lane & 15);
#pragma unroll
        for (int s = 0; s < 8; ++s) {
            int k = s * 32 + kq;
            const u32* p = (k < 128) ? (Wl + ((size_t)o * 128 + k) / 2)
                                     : (Wr + ((size_t)o * 128 + (k - 128)) / 2);
            bf16x8 b = *(const bf16x8*)p;
            acc[c] = __builtin_amdgcn_mfma_f32_16x16x32_bf16(afrag[s], b, acc[c], 0, 0, 0);
        }
    }

#pragma unroll
    for (int c = 0; c < 8; ++c) {
        int o = c * 16 + (lane & 15);
        float bv = bias[o];
#pragma unroll
        for (int r = 0; r < 4; ++r) {
            int m = m0 + (lane >> 4) * 4 + r;
            float v = acc[c][r] + bv;
            v = (ACT == 0) ? fmaxf(v, 0.f) : ((v > 0.f) ? v : expm1f(v));
            Out[(size_t)m * 128 + o] = f2bf(v);
        }
    }
}

// ---------------- layer 3: y = h2@W2l^T, r = h2@W2r^T + b  (both [N,8] f32) -------
__device__ __forceinline__ float dot8(uint4 a, uint4 b, float acc) {
    const u32* pa = (const u32*)&a;
    const u32* pb = (const u32*)&b;
#pragma unroll
    for (int t = 0; t < 4; ++t) {
        acc = fmaf(__uint_as_float(pa[t] << 16), __uint_as_float(pb[t] << 16), acc);
        acc = fmaf(__uint_as_float(pa[t] & 0xffff0000u),
                   __uint_as_float(pb[t] & 0xffff0000u), acc);
    }
    return acc;
}

__global__ __launch_bounds__(256) void k_lin8(const u16* Xin, const u32* Wl,
                                              const u32* Wr, const float* bias,
                                              float* Y, float* R, int N) {
    int t = blockIdx.x * 256 + threadIdx.x;
    int n = t >> 3;
    int o = t & 7;
    if (n >= N) return;
    const uint4* xr = (const uint4*)(Xin + (size_t)n * 128);
    const uint4* wl = (const uint4*)(Wl + (size_t)o * 64);
    const uint4* wr = (const uint4*)(Wr + (size_t)o * 64);
    float al = 0.f, ar = bias[o];
#pragma unroll
    for (int i = 0; i < 16; ++i) {
        uint4 xv = xr[i];
        al = dot8(xv, wl[i], al);
        ar = dot8(xv, wr[i], ar);
    }
    Y[(size_t)n * 8 + o] = al;
    R[(size_t)n * 8 + o] = ar;
}

// mean-aggregate Y (f32 [N,8], 1.6 MB -> L2-resident) + r + log_softmax.
__global__ __launch_bounds__(256) void k_agg8sm(const float* Y, const float* R,
                                                const int* rowptr, const int* adj,
                                                const int* flag, void* Out,
                                                int N, int E) {
    int t = blockIdx.x * 256 + threadIdx.x;
    int n = t >> 3;
    int o = t & 7;
    if (n >= N) return;
    int beg = rowptr[n], end = rowptr[n + 1];
    beg = min(max(beg, 0), E);
    end = min(max(end, beg), E);
    float s = 0.f;
    int j = beg;
    for (; j + 1 < end; j += 2) {
        int a0 = min(max(adj[j], 0), N - 1);
        int a1 = min(max(adj[j + 1], 0), N - 1);
        s += Y[(size_t)a0 * 8 + o];
        s += Y[(size_t)a1 * 8 + o];
    }
    if (j < end) {
        int a0 = min(max(adj[j], 0), N - 1);
        s += Y[(size_t)a0 * 8 + o];
    }
    float acc = s / fmaxf((float)(end - beg), 1.f) + R[(size_t)n * 8 + o];
    float mx = acc;
#pragma unroll
    for (int d = 1; d < 8; d <<= 1) mx = fmaxf(mx, __shfl_xor(mx, d, 64));
    float ex = expf(acc - mx), se = ex;
#pragma unroll
    for (int d = 1; d < 8; d <<= 1) se += __shfl_xor(se, d, 64);
    float v = acc - mx - logf(se);
    if (*flag) ((float*)Out)[(size_t)n * 8 + o] = v;
    else       ((u16*)Out)[(size_t)n * 8 + o] = f2bf(v);
}

// ---------------- launch ----------------
extern "C" void kernel_launch(void* const* d_in, const int* in_sizes, int n_in,
                              void* d_out, int out_size, void* d_ws, size_t ws_size,
                              hipStream_t stream) {
    const void* x   = d_in[0];
    const int* ei   = (const int*)d_in[1];
    const int N = in_sizes[0] / 128;
    const int E = in_sizes[1] / 2;
    const int* srcv = ei;
    const int* dstv = ei + E;
    const int NBUK = (N + 255) >> 8;         // buckets of 256 nodes
    const bool bucketed = (N <= 65536) && (NBUK <= 256);

    auto rnd = [](size_t b) { return (b + 255) & ~(size_t)255; };
    size_t need = rnd(256)                    // flag
                + rnd((size_t)N * 4)          // deg
                + rnd((size_t)(N + 1) * 4)    // rowptr
                + rnd(4096)                   // bsums
                + rnd(1024)                   // gcur
                + rnd((size_t)E * 4)          // adj
                + 2 * rnd((size_t)N * 256)    // X, A
                + 4 * rnd(32768) + 2 * rnd(2048) + 2 * rnd(512) + rnd(64);
    if (ws_size < need) {
        k_sentinel<<<(out_size + 255) / 256, 256, 0, stream>>>((u16*)d_out, out_size);
        return;
    }

    char* p = (char*)d_ws;
    auto carve = [&](size_t bytes) { char* r = p; p += (bytes + 255) & ~(size_t)255; return r; };
    int* flag   = (int*)carve(256);
    int* deg    = (int*)carve((size_t)N * 4);
    int* rowptr = (int*)carve((size_t)(N + 1) * 4);
    int* bsums  = (int*)carve(4096);
    int* gcur   = (int*)carve(1024);
    int* adj    = (int*)carve((size_t)E * 4);
    u32* X      = (u32*)carve((size_t)N * 256);   // [N,128] packed bf16
    u32* A      = (u32*)carve((size_t)N * 256);   // agg buffer; dead until 1st aggregate
    u32* w1l = (u32*)carve(32768); u32* w1r = (u32*)carve(32768);
    u32* whl = (u32*)carve(32768); u32* whr = (u32*)carve(32768);
    u32* w2l = (u32*)carve(2048);  u32* w2r = (u32*)carve(2048);
    float* bf1 = (float*)carve(512); float* bfh = (float*)carve(512);
    float* bf2 = (float*)carve(64);
    // pairs (E u32 = 3.2 MB) aliases A: fully consumed by k_fillb before aggregate
    u32* pairs = A;
    // layer-3 Y/R ([N,8] f32 = 1.6 MB each) also live in dead A
    float* Y = (float*)A;
    float* R = Y + (size_t)N * 8;
    (void)n_in;

    k_detect<<<1, 64, 0, stream>>>((const u32*)x, flag);

    // canonicalize inputs
    k_cvt<<<(N * 64 + 255) / 256, 256, 0, stream>>>(x, flag, X, N * 64);
    k_cvtp<<<134, 256, 0, stream>>>(d_in[3], d_in[5], d_in[6], d_in[8], d_in[9],
                                    d_in[11], d_in[4], d_in[7], d_in[10], flag,
                                    w1l, w1r, whl, whr, w2l, w2r, bf1, bfh, bf2);

    // CSR build
    hipMemsetAsync(deg, 0, (size_t)N * 4, stream);
    int nb = (N + 511) / 512;
    k_deg<<<(E + 255) / 256, 256, 0, stream>>>(dstv, deg, E, N);
    k_scan1<<<nb, 512, 0, stream>>>(deg, rowptr, bsums, N);
    k_scan2<<<1, 128, 0, stream>>>(bsums, nb);
    k_scan3<<<nb, 512, 0, stream>>>(rowptr, bsums, gcur, N, E);
    if (bucketed) {
        k_bucket<<<(E + EB_CHUNK - 1) / EB_CHUNK, 256, 0, stream>>>(
            srcv, dstv, gcur, pairs, E, N, NBUK);
        k_fillb<<<NBUK, 256, 0, stream>>>(pairs, rowptr, deg, adj, E, N);
    } else {
        k_fill<<<(E + 255) / 256, 256, 0, stream>>>(srcv, dstv, rowptr, deg, adj, E, N);
    }

    int aggBlocks = (int)(((size_t)N * 64 + 255) / 256);
    int gemmBlocks = ((N + 15) / 16 + 3) / 4;
    int perNode8 = (int)(((size_t)N * 8 + 255) / 256);

    // L1: A=mean(X); h1=relu(A@W1l^T+b1+X@W1r^T) -> X (own-rows aliasing, safe)
    k_aggregate<<<aggBlocks, 256, 0, stream>>>((const uint4*)X, rowptr, adj, (uint4*)A, N, E);
    k_gemm128<0><<<gemmBlocks, 256, 0, stream>>>((const u16*)A, (const u16*)X, w1l, w1r, bf1, (u16*)X, N);
    // L2: A=mean(h1=X); h2=elu(A@Whl^T+bh+X@Whr^T) -> X
    k_aggregate<<<aggBlocks, 256, 0, stream>>>((const uint4*)X, rowptr, adj, (uint4*)A, N, E);
    k_gemm128<1><<<gemmBlocks, 256, 0, stream>>>((const u16*)A, (const u16*)X, whl, whr, bfh, (u16*)X, N);
    // L3 (linearity): y=h2@W2l^T, r=h2@W2r^T+b2; out = log_softmax(mean_agg(y)+r)
    k_lin8<<<perNode8, 256, 0, stream>>>((const u16*)X, w2l, w2r, bf2, Y, R, N);
    k_agg8sm<<<perNode8, 256, 0, stream>>>(Y, R, rowptr, adj, flag, d_out, N, E);
}

// Round 7
// 341.546 us; speedup vs baseline: 2.0572x; 1.0738x over previous
//
#include <hip/hip_runtime.h>

typedef unsigned int u32;
typedef unsigned short u16;
typedef short bf16x8 __attribute__((ext_vector_type(8)));   // 8 bf16 (4 VGPRs)
typedef float f32x4 __attribute__((ext_vector_type(4)));    // MFMA accumulator

#define NCB 256   // blocks for count/place passes

__device__ __forceinline__ float bf2f(u16 h) { return __uint_as_float(((u32)h) << 16); }
__device__ __forceinline__ u16 f2bf(float f) {
    u32 u = __float_as_uint(f);
    return (u16)((u + 0x7fffu + ((u >> 16) & 1u)) >> 16);   // RNE
}

// ---------------- diagnostic fallback: ws too small ----------------
__global__ __launch_bounds__(256) void k_sentinel(u16* out, int n) {
    int i = blockIdx.x * 256 + threadIdx.x;
    if (i < n) out[i] = f2bf(-7.0f);
}

// ---------------- dtype detection: flag=0 bf16-packed, flag=1 f32 ----------------
__global__ void k_detect(const u32* x, int* flag) {
    int lane = threadIdx.x;  // 64 threads
    int c = 0;
    for (int j = 0; j < 4; ++j) {
        u32 u = x[lane * 4 + j];
        u32 e = (u >> 7) & 0xffu;
        if ((e >= 0x30u && e <= 0x47u) || ((u & 0x7fffu) == 0u)) ++c;
    }
    for (int d = 32; d; d >>= 1) c += __shfl_down(c, d, 64);
    if (lane == 0) *flag = (c < 128) ? 1 : 0;
}

// ---------------- converters into canonical packed-bf16 / f32 ----------------
__global__ __launch_bounds__(256) void k_cvt(const void* src, const int* flag,
                                             u32* dst, int n) {  // n = u32 words out
    int i = blockIdx.x * 256 + threadIdx.x;
    if (i >= n) return;
    if (*flag) {
        const float* s = (const float*)src;
        dst[i] = (u32)f2bf(s[2 * i]) | ((u32)f2bf(s[2 * i + 1]) << 16);
    } else {
        dst[i] = ((const u32*)src)[i];
    }
}

// fused parameter conversion
__global__ __launch_bounds__(256) void k_cvtp(
    const void* s1l, const void* s1r, const void* shl, const void* shr,
    const void* s2l, const void* s2r, const void* sb1, const void* sbh,
    const void* sb2, const int* flag,
    u32* w1l, u32* w1r, u32* whl, u32* whr, u32* w2l, u32* w2r,
    float* bf1, float* bfh, float* bf2) {
    int b = blockIdx.x, t = threadIdx.x;
    int fl = *flag;
    auto cv = [&](const void* src, u32* dst, int base) {
        int i = base + t;
        if (fl) {
            const float* s = (const float*)src;
            dst[i] = (u32)f2bf(s[2 * i]) | ((u32)f2bf(s[2 * i + 1]) << 16);
        } else {
            dst[i] = ((const u32*)src)[i];
        }
    };
    auto cb = [&](const void* src, float* dst, int i) {
        dst[i] = fl ? ((const float*)src)[i] : bf2f(((const u16*)src)[i]);
    };
    if      (b <  32) cv(s1l, w1l, b * 256);
    else if (b <  64) cv(s1r, w1r, (b - 32) * 256);
    else if (b <  96) cv(shl, whl, (b - 64) * 256);
    else if (b < 128) cv(shr, whr, (b - 96) * 256);
    else if (b < 130) cv(s2l, w2l, (b - 128) * 256);
    else if (b < 132) cv(s2r, w2r, (b - 130) * 256);
    else if (b == 132) {
        if (t < 128) cb(sb1, bf1, t);
        else         cb(sbh, bfh, t - 128);
    } else {
        if (t < 8) cb(sb2, bf2, t);
    }
}

// ---------------- CSR build ----------------
// Pass A: per-node degree (global atomics, ~16/addr) + count matrix C[bucket][block]
// via LDS histogram + plain stores. NO contended global atomics.
__global__ __launch_bounds__(256) void k_count(const int* dstv, int* deg, int* C,
                                               int E, int N, int chunk) {
    __shared__ int hist[256];
    int t = threadIdx.x;
    hist[t] = 0;
    __syncthreads();
    int e0 = blockIdx.x * chunk;
    int e1 = min(e0 + chunk, E);
    for (int e = e0 + t; e < e1; e += 256) {
        int d = min(max(dstv[e], 0), N - 1);
        atomicAdd(&deg[d], 1);
        atomicAdd(&hist[d >> 8], 1);
    }
    __syncthreads();
    C[t * NCB + blockIdx.x] = hist[t];   // row t = bucket t (nbuk <= 256)
}

__global__ __launch_bounds__(512) void k_scan1(const int* deg, int* rowptr,
                                               int* bsums, int N) {
    __shared__ int sm[512];
    int i = blockIdx.x * 512 + threadIdx.x;
    int v = (i < N) ? deg[i] : 0;
    sm[threadIdx.x] = v;
    __syncthreads();
    for (int off = 1; off < 512; off <<= 1) {
        int t = (threadIdx.x >= off) ? sm[threadIdx.x - off] : 0;
        __syncthreads();
        sm[threadIdx.x] += t;
        __syncthreads();
    }
    if (i < N) rowptr[i] = sm[threadIdx.x] - v;            // exclusive
    if (threadIdx.x == 511) bsums[blockIdx.x] = sm[511];
}

__global__ __launch_bounds__(128) void k_scan2(int* bsums, int nb) {
    __shared__ int sm[128];
    int v = (threadIdx.x < nb) ? bsums[threadIdx.x] : 0;
    sm[threadIdx.x] = v;
    __syncthreads();
    for (int off = 1; off < 128; off <<= 1) {
        int t = (threadIdx.x >= off) ? sm[threadIdx.x - off] : 0;
        __syncthreads();
        sm[threadIdx.x] += t;
        __syncthreads();
    }
    if (threadIdx.x < nb) bsums[threadIdx.x] = sm[threadIdx.x] - v;  // exclusive
}

// finalize rowptr; sample bucket starts gcur[b] = rowptr[256*b]
__global__ __launch_bounds__(512) void k_scan3(int* rowptr, const int* bsums,
                                               int* gcur, int N, int E) {
    int i = blockIdx.x * 512 + threadIdx.x;
    if (i < N) {
        int v = rowptr[i] + bsums[blockIdx.x];
        rowptr[i] = v;
        if ((i & 255) == 0) gcur[i >> 8] = v;
    }
    if (i == 0) rowptr[N] = E;
}

// Pass B: exclusive scan of C[b][.] across NCB blocks + bucket start -> per-(block,
// bucket) base offsets. One block per bucket; no atomics.
__global__ __launch_bounds__(NCB) void k_scanC(int* C, const int* gcur) {
    __shared__ int sm[NCB];
    int b = blockIdx.x, t = threadIdx.x;
    int v = C[b * NCB + t];
    sm[t] = v;
    __syncthreads();
    for (int off = 1; off < NCB; off <<= 1) {
        int u = (t >= off) ? sm[t - off] : 0;
        __syncthreads();
        sm[t] += u;
        __syncthreads();
    }
    C[b * NCB + t] = sm[t] - v + gcur[b];
}

// Pass C: place edges into bucket-segmented pairs using precomputed bases.
// LDS cnt chains ~chunk/nbuk (~12) per bucket; global writes in ~48B dense runs.
__global__ __launch_bounds__(256) void k_place(const int* srcv, const int* dstv,
                                               const int* C, u32* pairs,
                                               int E, int N, int chunk) {
    __shared__ int base[256], cnt[256];
    int t = threadIdx.x;
    base[t] = C[t * NCB + blockIdx.x];
    cnt[t] = 0;
    __syncthreads();
    int e0 = blockIdx.x * chunk;
    int e1 = min(e0 + chunk, E);
    for (int e = e0 + t; e < e1; e += 256) {
        int d = min(max(dstv[e], 0), N - 1);
        int s = min(max(srcv[e], 0), N - 1);
        int b = d >> 8;
        int pos = base[b] + atomicAdd(&cnt[b], 1);
        pos = min(max(pos, 0), E - 1);
        pairs[pos] = ((u32)s << 8) | (u32)(d & 255);
    }
}

// Pass D: one block per bucket; LDS countdown cursors; adj writes confined to the
// bucket's ~16KB XCD-exclusive window.
__global__ __launch_bounds__(256) void k_fillb(const u32* pairs, const int* rowptr,
                                               const int* deg, int* adj, int E, int N) {
    int b = blockIdx.x;
    int n0 = b << 8;
    int nn = min(N - n0, 256);
    __shared__ int cur[256];
    int t = threadIdx.x;
    if (t < nn) cur[t] = deg[n0 + t];
    __syncthreads();
    int s0 = rowptr[n0];
    int s1 = rowptr[min(n0 + 256, N)];
    s0 = min(max(s0, 0), E);
    s1 = min(max(s1, s0), E);
    for (int e = s0 + t; e < s1; e += 256) {
        u32 pc = pairs[e];
        int ld = (int)(pc & 255u);
        ld = min(ld, nn - 1);
        int src = (int)(pc >> 8);
        int slot = atomicSub(&cur[ld], 1) - 1;
        int idx = rowptr[n0 + ld] + slot;
        idx = min(max(idx, 0), E - 1);
        adj[idx] = src;
    }
}

// fallback path for big N: plain degree count + direct scatter
__global__ __launch_bounds__(256) void k_deg(const int* dstv, int* deg, int E, int N) {
    int e = blockIdx.x * 256 + threadIdx.x;
    if (e >= E) return;
    int d = dstv[e]; d = min(max(d, 0), N - 1);
    atomicAdd(&deg[d], 1);
}

__global__ __launch_bounds__(256) void k_fill(const int* srcv, const int* dstv,
                                              const int* rowptr, int* deg,
                                              int* adj, int E, int N) {
    int e = blockIdx.x * 256 + threadIdx.x;
    if (e >= E) return;
    int d = dstv[e]; d = min(max(d, 0), N - 1);
    int slot = atomicSub(&deg[d], 1) - 1;
    int idx = rowptr[d] + slot;
    idx = min(max(idx, 0), E - 1);
    adj[idx] = srcv[e];
}

// ---------------- mean aggregation: one wave per node, 4x16-lane groups, unroll 4 --
__device__ __forceinline__ void acc8(uint4 u, float* s) {
    const u32* pu = (const u32*)&u;
#pragma unroll
    for (int t = 0; t < 4; ++t) {
        s[2 * t]     += __uint_as_float(pu[t] << 16);
        s[2 * t + 1] += __uint_as_float(pu[t] & 0xffff0000u);
    }
}

__global__ __launch_bounds__(256) void k_aggregate(const uint4* F, const int* rowptr,
                                                   const int* adj, uint4* A,
                                                   int N, int E) {
    int wid = (int)((blockIdx.x * 256u + threadIdx.x) >> 6);
    int lane = threadIdx.x & 63;
    if (wid >= N) return;
    int beg = rowptr[wid], end = rowptr[wid + 1];
    beg = min(max(beg, 0), E);
    end = min(max(end, beg), E);
    int g = lane >> 4, l = lane & 15;
    float s[8] = {0.f, 0.f, 0.f, 0.f, 0.f, 0.f, 0.f, 0.f};
    int j = beg + g;
    for (; j + 12 < end; j += 16) {
        int a0 = min(max(adj[j], 0), N - 1);
        int a1 = min(max(adj[j + 4], 0), N - 1);
        int a2 = min(max(adj[j + 8], 0), N - 1);
        int a3 = min(max(adj[j + 12], 0), N - 1);
        uint4 u0 = F[(size_t)a0 * 16 + l];
        uint4 u1 = F[(size_t)a1 * 16 + l];
        uint4 u2 = F[(size_t)a2 * 16 + l];
        uint4 u3 = F[(size_t)a3 * 16 + l];
        acc8(u0, s); acc8(u1, s); acc8(u2, s); acc8(u3, s);
    }
    for (; j < end; j += 4) {
        int a0 = min(max(adj[j], 0), N - 1);
        uint4 u0 = F[(size_t)a0 * 16 + l];
        acc8(u0, s);
    }
#pragma unroll
    for (int k = 0; k < 8; ++k) {
        s[k] += __shfl_xor(s[k], 16, 64);
        s[k] += __shfl_xor(s[k], 32, 64);
    }
    if (g == 0) {
        float inv = 1.f / fmaxf((float)(end - beg), 1.f);
        uint4 r; u32* pr = (u32*)&r;
#pragma unroll
        for (int t = 0; t < 4; ++t)
            pr[t] = (u32)f2bf(s[2 * t] * inv) | ((u32)f2bf(s[2 * t + 1] * inv) << 16);
        A[(size_t)wid * 16 + l] = r;
    }
}

// ---------------- fused SAGE GEMM: h = act(Agg@Wl^T + b + Xin@Wr^T) ----------------
template <int ACT>  // 0 = relu, 1 = elu
__global__ __launch_bounds__(256) void k_gemm128(const u16* Agg, const u16* Xin,
                                                 const u32* Wl, const u32* Wr,
                                                 const float* bias, u16* Out, int N) {
    int tile = blockIdx.x * 4 + (threadIdx.x >> 6);
    int lane = threadIdx.x & 63;
    int m0 = tile * 16;
    if (m0 >= N) return;
    int mrow = m0 + (lane & 15);
    int kq = (lane >> 4) * 8;

    bf16x8 afrag[8];
#pragma unroll
    for (int s = 0; s < 8; ++s) {
        int k = s * 32 + kq;
        const u16* p = (k < 128) ? (Agg + (size_t)mrow * 128 + k)
                                 : (Xin + (size_t)mrow * 128 + (k - 128));
        afrag[s] = *(const bf16x8*)p;
    }

    f32x4 acc[8];
#pragma unroll
    for (int c = 0; c < 8; ++c) acc[c] = (f32x4){0.f, 0.f, 0.f, 0.f};

#pragma unroll
    for (int c = 0; c < 8; ++c) {
        int o = c * 16 + (lane & 15);
#pragma unroll
        for (int s = 0; s < 8; ++s) {
            int k = s * 32 + kq;
            const u32* p = (k < 128) ? (Wl + ((size_t)o * 128 + k) / 2)
                                     : (Wr + ((size_t)o * 128 + (k - 128)) / 2);
            bf16x8 b = *(const bf16x8*)p;
            acc[c] = __builtin_amdgcn_mfma_f32_16x16x32_bf16(afrag[s], b, acc[c], 0, 0, 0);
        }
    }

#pragma unroll
    for (int c = 0; c < 8; ++c) {
        int o = c * 16 + (lane & 15);
        float bv = bias[o];
#pragma unroll
        for (int r = 0; r < 4; ++r) {
            int m = m0 + (lane >> 4) * 4 + r;
            float v = acc[c][r] + bv;
            v = (ACT == 0) ? fmaxf(v, 0.f) : ((v > 0.f) ? v : expm1f(v));
            Out[(size_t)m * 128 + o] = f2bf(v);
        }
    }
}

// ---------------- layer 3: y = h2@W2l^T, r = h2@W2r^T + b  (both [N,8] f32) -------
__device__ __forceinline__ float dot8(uint4 a, uint4 b, float acc) {
    const u32* pa = (const u32*)&a;
    const u32* pb = (const u32*)&b;
#pragma unroll
    for (int t = 0; t < 4; ++t) {
        acc = fmaf(__uint_as_float(pa[t] << 16), __uint_as_float(pb[t] << 16), acc);
        acc = fmaf(__uint_as_float(pa[t] & 0xffff0000u),
                   __uint_as_float(pb[t] & 0xffff0000u), acc);
    }
    return acc;
}

__global__ __launch_bounds__(256) void k_lin8(const u16* Xin, const u32* Wl,
                                              const u32* Wr, const float* bias,
                                              float* Y, float* R, int N) {
    int t = blockIdx.x * 256 + threadIdx.x;
    int n = t >> 3;
    int o = t & 7;
    if (n >= N) return;
    const uint4* xr = (const uint4*)(Xin + (size_t)n * 128);
    const uint4* wl = (const uint4*)(Wl + (size_t)o * 64);
    const uint4* wr = (const uint4*)(Wr + (size_t)o * 64);
    float al = 0.f, ar = bias[o];
#pragma unroll
    for (int i = 0; i < 16; ++i) {
        uint4 xv = xr[i];
        al = dot8(xv, wl[i], al);
        ar = dot8(xv, wr[i], ar);
    }
    Y[(size_t)n * 8 + o] = al;
    R[(size_t)n * 8 + o] = ar;
}

// mean-aggregate Y (f32 [N,8], 1.6 MB -> L2-resident) + r + log_softmax.
__global__ __launch_bounds__(256) void k_agg8sm(const float* Y, const float* R,
                                                const int* rowptr, const int* adj,
                                                const int* flag, void* Out,
                                                int N, int E) {
    int t = blockIdx.x * 256 + threadIdx.x;
    int n = t >> 3;
    int o = t & 7;
    if (n >= N) return;
    int beg = rowptr[n], end = rowptr[n + 1];
    beg = min(max(beg, 0), E);
    end = min(max(end, beg), E);
    float s = 0.f;
    int j = beg;
    for (; j + 1 < end; j += 2) {
        int a0 = min(max(adj[j], 0), N - 1);
        int a1 = min(max(adj[j + 1], 0), N - 1);
        s += Y[(size_t)a0 * 8 + o];
        s += Y[(size_t)a1 * 8 + o];
    }
    if (j < end) {
        int a0 = min(max(adj[j], 0), N - 1);
        s += Y[(size_t)a0 * 8 + o];
    }
    float acc = s / fmaxf((float)(end - beg), 1.f) + R[(size_t)n * 8 + o];
    float mx = acc;
#pragma unroll
    for (int d = 1; d < 8; d <<= 1) mx = fmaxf(mx, __shfl_xor(mx, d, 64));
    float ex = expf(acc - mx), se = ex;
#pragma unroll
    for (int d = 1; d < 8; d <<= 1) se += __shfl_xor(se, d, 64);
    float v = acc - mx - logf(se);
    if (*flag) ((float*)Out)[(size_t)n * 8 + o] = v;
    else       ((u16*)Out)[(size_t)n * 8 + o] = f2bf(v);
}

// ---------------- launch ----------------
extern "C" void kernel_launch(void* const* d_in, const int* in_sizes, int n_in,
                              void* d_out, int out_size, void* d_ws, size_t ws_size,
                              hipStream_t stream) {
    const void* x   = d_in[0];
    const int* ei   = (const int*)d_in[1];
    const int N = in_sizes[0] / 128;
    const int E = in_sizes[1] / 2;
    const int* srcv = ei;
    const int* dstv = ei + E;
    const int NBUK = (N + 255) >> 8;         // buckets of 256 nodes
    const bool bucketed = (NBUK <= 256);     // 256-entry LDS hist; src fits 24 bits
    const int chunk = (E + NCB - 1) / NCB;

    auto rnd = [](size_t b) { return (b + 255) & ~(size_t)255; };
    size_t need = rnd(256)                    // flag
                + rnd((size_t)N * 4)          // deg
                + rnd((size_t)(N + 1) * 4)    // rowptr
                + rnd(4096)                   // bsums
                + rnd(1024)                   // gcur
                + rnd(256 * NCB * 4)          // C matrix
                + rnd((size_t)E * 4)          // adj
                + 2 * rnd((size_t)N * 256)    // X, A
                + 4 * rnd(32768) + 2 * rnd(2048) + 2 * rnd(512) + rnd(64);
    if (ws_size < need) {
        k_sentinel<<<(out_size + 255) / 256, 256, 0, stream>>>((u16*)d_out, out_size);
        return;
    }

    char* p = (char*)d_ws;
    auto carve = [&](size_t bytes) { char* r = p; p += (bytes + 255) & ~(size_t)255; return r; };
    int* flag   = (int*)carve(256);
    int* deg    = (int*)carve((size_t)N * 4);
    int* rowptr = (int*)carve((size_t)(N + 1) * 4);
    int* bsums  = (int*)carve(4096);
    int* gcur   = (int*)carve(1024);
    int* C      = (int*)carve(256 * NCB * 4);
    int* adj    = (int*)carve((size_t)E * 4);
    u32* X      = (u32*)carve((size_t)N * 256);   // [N,128] packed bf16
    u32* A      = (u32*)carve((size_t)N * 256);   // agg buffer; dead until 1st aggregate
    u32* w1l = (u32*)carve(32768); u32* w1r = (u32*)carve(32768);
    u32* whl = (u32*)carve(32768); u32* whr = (u32*)carve(32768);
    u32* w2l = (u32*)carve(2048);  u32* w2r = (u32*)carve(2048);
    float* bf1 = (float*)carve(512); float* bfh = (float*)carve(512);
    float* bf2 = (float*)carve(64);
    // pairs (E u32 = 3.2 MB) aliases A: fully consumed by k_fillb before aggregate
    u32* pairs = A;
    // layer-3 Y/R ([N,8] f32 = 1.6 MB each) also live in dead A
    float* Y = (float*)A;
    float* R = Y + (size_t)N * 8;
    (void)n_in;

    k_detect<<<1, 64, 0, stream>>>((const u32*)x, flag);

    // canonicalize inputs
    k_cvt<<<(N * 64 + 255) / 256, 256, 0, stream>>>(x, flag, X, N * 64);
    k_cvtp<<<134, 256, 0, stream>>>(d_in[3], d_in[5], d_in[6], d_in[8], d_in[9],
                                    d_in[11], d_in[4], d_in[7], d_in[10], flag,
                                    w1l, w1r, whl, whr, w2l, w2r, bf1, bfh, bf2);

    // CSR build
    hipMemsetAsync(deg, 0, (size_t)N * 4, stream);
    int nb = (N + 511) / 512;
    if (bucketed) {
        k_count<<<NCB, 256, 0, stream>>>(dstv, deg, C, E, N, chunk);
        k_scan1<<<nb, 512, 0, stream>>>(deg, rowptr, bsums, N);
        k_scan2<<<1, 128, 0, stream>>>(bsums, nb);
        k_scan3<<<nb, 512, 0, stream>>>(rowptr, bsums, gcur, N, E);
        k_scanC<<<NBUK, NCB, 0, stream>>>(C, gcur);
        k_place<<<NCB, 256, 0, stream>>>(srcv, dstv, C, pairs, E, N, chunk);
        k_fillb<<<NBUK, 256, 0, stream>>>(pairs, rowptr, deg, adj, E, N);
    } else {
        k_deg<<<(E + 255) / 256, 256, 0, stream>>>(dstv, deg, E, N);
        k_scan1<<<nb, 512, 0, stream>>>(deg, rowptr, bsums, N);
        k_scan2<<<1, 128, 0, stream>>>(bsums, nb);
        k_scan3<<<nb, 512, 0, stream>>>(rowptr, bsums, gcur, N, E);
        k_fill<<<(E + 255) / 256, 256, 0, stream>>>(srcv, dstv, rowptr, deg, adj, E, N);
    }

    int aggBlocks = (int)(((size_t)N * 64 + 255) / 256);
    int gemmBlocks = ((N + 15) / 16 + 3) / 4;
    int perNode8 = (int)(((size_t)N * 8 + 255) / 256);

    // L1: A=mean(X); h1=relu(A@W1l^T+b1+X@W1r^T) -> X (own-rows aliasing, safe)
    k_aggregate<<<aggBlocks, 256, 0, stream>>>((const uint4*)X, rowptr, adj, (uint4*)A, N, E);
    k_gemm128<0><<<gemmBlocks, 256, 0, stream>>>((const u16*)A, (const u16*)X, w1l, w1r, bf1, (u16*)X, N);
    // L2: A=mean(h1=X); h2=elu(A@Whl^T+bh+X@Whr^T) -> X
    k_aggregate<<<aggBlocks, 256, 0, stream>>>((const uint4*)X, rowptr, adj, (uint4*)A, N, E);
    k_gemm128<1><<<gemmBlocks, 256, 0, stream>>>((const u16*)A, (const u16*)X, whl, whr, bfh, (u16*)X, N);
    // L3 (linearity): y=h2@W2l^T, r=h2@W2r^T+b2; out = log_softmax(mean_agg(y)+r)
    k_lin8<<<perNode8, 256, 0, stream>>>((const u16*)X, w2l, w2r, bf2, Y, R, N);
    k_agg8sm<<<perNode8, 256, 0, stream>>>(Y, R, rowptr, adj, flag, d_out, N, E);
}

// Round 8
// 309.945 us; speedup vs baseline: 2.2669x; 1.1020x over previous
//
#include <hip/hip_runtime.h>

typedef unsigned int u32;
typedef unsigned short u16;
typedef short bf16x8 __attribute__((ext_vector_type(8)));   // 8 bf16 (4 VGPRs)
typedef float f32x4 __attribute__((ext_vector_type(4)));    // MFMA accumulator

#define NCB 256   // blocks for count/place passes

__device__ __forceinline__ float bf2f(u16 h) { return __uint_as_float(((u32)h) << 16); }
__device__ __forceinline__ u16 f2bf(float f) {
    u32 u = __float_as_uint(f);
    return (u16)((u + 0x7fffu + ((u >> 16) & 1u)) >> 16);   // RNE
}

// ---------------- diagnostic fallback: ws too small ----------------
__global__ __launch_bounds__(256) void k_sentinel(u16* out, int n) {
    int i = blockIdx.x * 256 + threadIdx.x;
    if (i < n) out[i] = f2bf(-7.0f);
}

// ---------------- dtype detection: flag=0 bf16-packed, flag=1 f32 ----------------
__global__ void k_detect(const u32* x, int* flag) {
    int lane = threadIdx.x;  // 64 threads
    int c = 0;
    for (int j = 0; j < 4; ++j) {
        u32 u = x[lane * 4 + j];
        u32 e = (u >> 7) & 0xffu;
        if ((e >= 0x30u && e <= 0x47u) || ((u & 0x7fffu) == 0u)) ++c;
    }
    for (int d = 32; d; d >>= 1) c += __shfl_down(c, d, 64);
    if (lane == 0) *flag = (c < 128) ? 1 : 0;
}

// ---------------- converters into canonical packed-bf16 / f32 ----------------
// vectorized: one uint4 (8 bf16) out per thread
__global__ __launch_bounds__(256) void k_cvt4(const void* src, const int* flag,
                                              uint4* dst, int n4) {
    int i = blockIdx.x * 256 + threadIdx.x;
    if (i >= n4) return;
    if (*flag) {
        const float4* s = (const float4*)src;
        float4 a = s[2 * i], b = s[2 * i + 1];
        uint4 o;
        o.x = (u32)f2bf(a.x) | ((u32)f2bf(a.y) << 16);
        o.y = (u32)f2bf(a.z) | ((u32)f2bf(a.w) << 16);
        o.z = (u32)f2bf(b.x) | ((u32)f2bf(b.y) << 16);
        o.w = (u32)f2bf(b.z) | ((u32)f2bf(b.w) << 16);
        dst[i] = o;
    } else {
        dst[i] = ((const uint4*)src)[i];
    }
}

// fused parameter conversion
__global__ __launch_bounds__(256) void k_cvtp(
    const void* s1l, const void* s1r, const void* shl, const void* shr,
    const void* s2l, const void* s2r, const void* sb1, const void* sbh,
    const void* sb2, const int* flag,
    u32* w1l, u32* w1r, u32* whl, u32* whr, u32* w2l, u32* w2r,
    float* bf1, float* bfh, float* bf2) {
    int b = blockIdx.x, t = threadIdx.x;
    int fl = *flag;
    auto cv = [&](const void* src, u32* dst, int base) {
        int i = base + t;
        if (fl) {
            const float* s = (const float*)src;
            dst[i] = (u32)f2bf(s[2 * i]) | ((u32)f2bf(s[2 * i + 1]) << 16);
        } else {
            dst[i] = ((const u32*)src)[i];
        }
    };
    auto cb = [&](const void* src, float* dst, int i) {
        dst[i] = fl ? ((const float*)src)[i] : bf2f(((const u16*)src)[i]);
    };
    if      (b <  32) cv(s1l, w1l, b * 256);
    else if (b <  64) cv(s1r, w1r, (b - 32) * 256);
    else if (b <  96) cv(shl, whl, (b - 64) * 256);
    else if (b < 128) cv(shr, whr, (b - 96) * 256);
    else if (b < 130) cv(s2l, w2l, (b - 128) * 256);
    else if (b < 132) cv(s2r, w2r, (b - 130) * 256);
    else if (b == 132) {
        if (t < 128) cb(sb1, bf1, t);
        else         cb(sbh, bfh, t - 128);
    } else {
        if (t < 8) cb(sb2, bf2, t);
    }
}

// ---------------- CSR build ----------------
__global__ __launch_bounds__(256) void k_count(const int* dstv, int* deg, int* C,
                                               int E, int N, int chunk) {
    __shared__ int hist[256];
    int t = threadIdx.x;
    hist[t] = 0;
    __syncthreads();
    int e0 = blockIdx.x * chunk;
    int e1 = min(e0 + chunk, E);
    for (int e = e0 + t; e < e1; e += 256) {
        int d = min(max(dstv[e], 0), N - 1);
        atomicAdd(&deg[d], 1);
        atomicAdd(&hist[d >> 8], 1);
    }
    __syncthreads();
    C[t * NCB + blockIdx.x] = hist[t];   // row t = bucket t (nbuk <= 256)
}

__global__ __launch_bounds__(512) void k_scan1(const int* deg, int* rowptr,
                                               int* bsums, int N) {
    __shared__ int sm[512];
    int i = blockIdx.x * 512 + threadIdx.x;
    int v = (i < N) ? deg[i] : 0;
    sm[threadIdx.x] = v;
    __syncthreads();
    for (int off = 1; off < 512; off <<= 1) {
        int t = (threadIdx.x >= off) ? sm[threadIdx.x - off] : 0;
        __syncthreads();
        sm[threadIdx.x] += t;
        __syncthreads();
    }
    if (i < N) rowptr[i] = sm[threadIdx.x] - v;            // exclusive
    if (threadIdx.x == 511) bsums[blockIdx.x] = sm[511];
}

__global__ __launch_bounds__(128) void k_scan2(int* bsums, int nb) {
    __shared__ int sm[128];
    int v = (threadIdx.x < nb) ? bsums[threadIdx.x] : 0;
    sm[threadIdx.x] = v;
    __syncthreads();
    for (int off = 1; off < 128; off <<= 1) {
        int t = (threadIdx.x >= off) ? sm[threadIdx.x - off] : 0;
        __syncthreads();
        sm[threadIdx.x] += t;
        __syncthreads();
    }
    if (threadIdx.x < nb) bsums[threadIdx.x] = sm[threadIdx.x] - v;  // exclusive
}

// finalize rowptr; sample bucket starts gcur[b] = rowptr[256*b]
__global__ __launch_bounds__(512) void k_scan3(int* rowptr, const int* bsums,
                                               int* gcur, int N, int E) {
    int i = blockIdx.x * 512 + threadIdx.x;
    if (i < N) {
        int v = rowptr[i] + bsums[blockIdx.x];
        rowptr[i] = v;
        if ((i & 255) == 0) gcur[i >> 8] = v;
    }
    if (i == 0) rowptr[N] = E;
}

__global__ __launch_bounds__(NCB) void k_scanC(int* C, const int* gcur) {
    __shared__ int sm[NCB];
    int b = blockIdx.x, t = threadIdx.x;
    int v = C[b * NCB + t];
    sm[t] = v;
    __syncthreads();
    for (int off = 1; off < NCB; off <<= 1) {
        int u = (t >= off) ? sm[t - off] : 0;
        __syncthreads();
        sm[t] += u;
        __syncthreads();
    }
    C[b * NCB + t] = sm[t] - v + gcur[b];
}

__global__ __launch_bounds__(256) void k_place(const int* srcv, const int* dstv,
                                               const int* C, u32* pairs,
                                               int E, int N, int chunk) {
    __shared__ int base[256], cnt[256];
    int t = threadIdx.x;
    base[t] = C[t * NCB + blockIdx.x];
    cnt[t] = 0;
    __syncthreads();
    int e0 = blockIdx.x * chunk;
    int e1 = min(e0 + chunk, E);
    for (int e = e0 + t; e < e1; e += 256) {
        int d = min(max(dstv[e], 0), N - 1);
        int s = min(max(srcv[e], 0), N - 1);
        int b = d >> 8;
        int pos = base[b] + atomicAdd(&cnt[b], 1);
        pos = min(max(pos, 0), E - 1);
        pairs[pos] = ((u32)s << 8) | (u32)(d & 255);
    }
}

__global__ __launch_bounds__(256) void k_fillb(const u32* pairs, const int* rowptr,
                                               const int* deg, int* adj, int E, int N) {
    int b = blockIdx.x;
    int n0 = b << 8;
    int nn = min(N - n0, 256);
    __shared__ int cur[256];
    int t = threadIdx.x;
    if (t < nn) cur[t] = deg[n0 + t];
    __syncthreads();
    int s0 = rowptr[n0];
    int s1 = rowptr[min(n0 + 256, N)];
    s0 = min(max(s0, 0), E);
    s1 = min(max(s1, s0), E);
    for (int e = s0 + t; e < s1; e += 256) {
        u32 pc = pairs[e];
        int ld = (int)(pc & 255u);
        ld = min(ld, nn - 1);
        int src = (int)(pc >> 8);
        int slot = atomicSub(&cur[ld], 1) - 1;
        int idx = rowptr[n0 + ld] + slot;
        idx = min(max(idx, 0), E - 1);
        adj[idx] = src;
    }
}

// fallback path for big N
__global__ __launch_bounds__(256) void k_deg(const int* dstv, int* deg, int E, int N) {
    int e = blockIdx.x * 256 + threadIdx.x;
    if (e >= E) return;
    int d = dstv[e]; d = min(max(d, 0), N - 1);
    atomicAdd(&deg[d], 1);
}

__global__ __launch_bounds__(256) void k_fill(const int* srcv, const int* dstv,
                                              const int* rowptr, int* deg,
                                              int* adj, int E, int N) {
    int e = blockIdx.x * 256 + threadIdx.x;
    if (e >= E) return;
    int d = dstv[e]; d = min(max(d, 0), N - 1);
    int slot = atomicSub(&deg[d], 1) - 1;
    int idx = rowptr[d] + slot;
    idx = min(max(idx, 0), E - 1);
    adj[idx] = srcv[e];
}

// ---------------- mean aggregation: one wave per node, 4x16-lane groups, unroll 4 --
__device__ __forceinline__ void acc8(uint4 u, float* s) {
    const u32* pu = (const u32*)&u;
#pragma unroll
    for (int t = 0; t < 4; ++t) {
        s[2 * t]     += __uint_as_float(pu[t] << 16);
        s[2 * t + 1] += __uint_as_float(pu[t] & 0xffff0000u);
    }
}

__global__ __launch_bounds__(256) void k_aggregate(const uint4* F, const int* rowptr,
                                                   const int* adj, uint4* A,
                                                   int N, int E) {
    int wid = (int)((blockIdx.x * 256u + threadIdx.x) >> 6);
    int lane = threadIdx.x & 63;
    if (wid >= N) return;
    int beg = rowptr[wid], end = rowptr[wid + 1];
    beg = min(max(beg, 0), E);
    end = min(max(end, beg), E);
    int g = lane >> 4, l = lane & 15;
    float s[8] = {0.f, 0.f, 0.f, 0.f, 0.f, 0.f, 0.f, 0.f};
    int j = beg + g;
    for (; j + 12 < end; j += 16) {
        int a0 = min(max(adj[j], 0), N - 1);
        int a1 = min(max(adj[j + 4], 0), N - 1);
        int a2 = min(max(adj[j + 8], 0), N - 1);
        int a3 = min(max(adj[j + 12], 0), N - 1);
        uint4 u0 = F[(size_t)a0 * 16 + l];
        uint4 u1 = F[(size_t)a1 * 16 + l];
        uint4 u2 = F[(size_t)a2 * 16 + l];
        uint4 u3 = F[(size_t)a3 * 16 + l];
        acc8(u0, s); acc8(u1, s); acc8(u2, s); acc8(u3, s);
    }
    for (; j < end; j += 4) {
        int a0 = min(max(adj[j], 0), N - 1);
        uint4 u0 = F[(size_t)a0 * 16 + l];
        acc8(u0, s);
    }
#pragma unroll
    for (int k = 0; k < 8; ++k) {
        s[k] += __shfl_xor(s[k], 16, 64);
        s[k] += __shfl_xor(s[k], 32, 64);
    }
    if (g == 0) {
        float inv = 1.f / fmaxf((float)(end - beg), 1.f);
        uint4 r; u32* pr = (u32*)&r;
#pragma unroll
        for (int t = 0; t < 4; ++t)
            pr[t] = (u32)f2bf(s[2 * t] * inv) | ((u32)f2bf(s[2 * t + 1] * inv) << 16);
        A[(size_t)wid * 16 + l] = r;
    }
}

// ---------------- fused SAGE GEMM: h = act(Agg@Wl^T + b + Xin@Wr^T) ----------------
// W' = Wl||Wr staged in LDS in MFMA B-fragment order: frag[c][s][q][n] (16B each),
// exactly 64 KB. K-loop = 64 ds_read_b128 + 64 MFMA per wave (no global B traffic).
// frag(c,s,q,n) = W'[o=c*16+n][k=s*32+q*8 .. +7]. Bank map: lane(n,q) -> words
// n*4+q*64: 256 distinct words, 8/bank = minimum -> no extra conflicts.
template <int ACT>  // 0 = relu, 1 = elu
__global__ __launch_bounds__(256) void k_gemm128(const u16* Agg, const u16* Xin,
                                                 const u32* Wl, const u32* Wr,
                                                 const float* bias, u16* Out, int N) {
    __shared__ __align__(16) u16 Wsh[32768];   // 64 KB -> 2 blocks/CU
    int t = threadIdx.x;
    // stage: 4096 frags, 16 per thread. f -> c=f>>9, s=(f>>6)&7, q=(f>>4)&3, n=f&15
#pragma unroll
    for (int i = 0; i < 16; ++i) {
        int f = i * 256 + t;
        int c = f >> 9, s = (f >> 6) & 7, q = (f >> 4) & 3, n = f & 15;
        int o = c * 16 + n;
        int k = s * 32 + q * 8;
        uint4 v;
        if (k < 128) v = *(const uint4*)(Wl + (size_t)o * 64 + (k >> 1));
        else         v = *(const uint4*)(Wr + (size_t)o * 64 + ((k - 128) >> 1));
        *(uint4*)(Wsh + f * 8) = v;
    }
    __syncthreads();

    int tile = blockIdx.x * 4 + (t >> 6);
    int lane = t & 63;
    int m0 = tile * 16;
    if (m0 >= N) return;
    int mrow = min(m0 + (lane & 15), N - 1);
    int kq = (lane >> 4) * 8;

    bf16x8 afrag[8];
#pragma unroll
    for (int s = 0; s < 8; ++s) {
        int k = s * 32 + kq;
        const u16* p = (k < 128) ? (Agg + (size_t)mrow * 128 + k)
                                 : (Xin + (size_t)mrow * 128 + (k - 128));
        afrag[s] = *(const bf16x8*)p;
    }

    f32x4 acc[8];
#pragma unroll
    for (int c = 0; c < 8; ++c) acc[c] = (f32x4){0.f, 0.f, 0.f, 0.f};

    // lane's LDS base: frag element n*16B within frag, frag idx (c*8+s)*4+q
    const u16* lbase = Wsh + (lane >> 4) * 128 + (lane & 15) * 8;  // q*16B*... in u16
#pragma unroll
    for (int c = 0; c < 8; ++c) {
#pragma unroll
        for (int s = 0; s < 8; ++s) {
            bf16x8 b = *(const bf16x8*)(lbase + (c * 8 + s) * 512);  // (c*8+s)*4 frags *128 u16
            acc[c] = __builtin_amdgcn_mfma_f32_16x16x32_bf16(afrag[s], b, acc[c], 0, 0, 0);
        }
    }

#pragma unroll
    for (int c = 0; c < 8; ++c) {
        int o = c * 16 + (lane & 15);
        float bv = bias[o];
#pragma unroll
        for (int r = 0; r < 4; ++r) {
            int m = m0 + (lane >> 4) * 4 + r;
            float v = acc[c][r] + bv;
            v = (ACT == 0) ? fmaxf(v, 0.f) : ((v > 0.f) ? v : expm1f(v));
            if (m < N) Out[(size_t)m * 128 + o] = f2bf(v);
        }
    }
}

// ---------------- layer 3: y = h2@W2l^T, r = h2@W2r^T + b  (both [N,8] f32) -------
__device__ __forceinline__ float dot8(uint4 a, uint4 b, float acc) {
    const u32* pa = (const u32*)&a;
    const u32* pb = (const u32*)&b;
#pragma unroll
    for (int t = 0; t < 4; ++t) {
        acc = fmaf(__uint_as_float(pa[t] << 16), __uint_as_float(pb[t] << 16), acc);
        acc = fmaf(__uint_as_float(pa[t] & 0xffff0000u),
                   __uint_as_float(pb[t] & 0xffff0000u), acc);
    }
    return acc;
}

__global__ __launch_bounds__(256) void k_lin8(const u16* Xin, const u32* Wl,
                                              const u32* Wr, const float* bias,
                                              float* Y, float* R, int N) {
    int t = blockIdx.x * 256 + threadIdx.x;
    int n = t >> 3;
    int o = t & 7;
    if (n >= N) return;
    const uint4* xr = (const uint4*)(Xin + (size_t)n * 128);
    const uint4* wl = (const uint4*)(Wl + (size_t)o * 64);
    const uint4* wr = (const uint4*)(Wr + (size_t)o * 64);
    float al = 0.f, ar = bias[o];
#pragma unroll
    for (int i = 0; i < 16; ++i) {
        uint4 xv = xr[i];
        al = dot8(xv, wl[i], al);
        ar = dot8(xv, wr[i], ar);
    }
    Y[(size_t)n * 8 + o] = al;
    R[(size_t)n * 8 + o] = ar;
}

__global__ __launch_bounds__(256) void k_agg8sm(const float* Y, const float* R,
                                                const int* rowptr, const int* adj,
                                                const int* flag, void* Out,
                                                int N, int E) {
    int t = blockIdx.x * 256 + threadIdx.x;
    int n = t >> 3;
    int o = t & 7;
    if (n >= N) return;
    int beg = rowptr[n], end = rowptr[n + 1];
    beg = min(max(beg, 0), E);
    end = min(max(end, beg), E);
    float s = 0.f;
    int j = beg;
    for (; j + 1 < end; j += 2) {
        int a0 = min(max(adj[j], 0), N - 1);
        int a1 = min(max(adj[j + 1], 0), N - 1);
        s += Y[(size_t)a0 * 8 + o];
        s += Y[(size_t)a1 * 8 + o];
    }
    if (j < end) {
        int a0 = min(max(adj[j], 0), N - 1);
        s += Y[(size_t)a0 * 8 + o];
    }
    float acc = s / fmaxf((float)(end - beg), 1.f) + R[(size_t)n * 8 + o];
    float mx = acc;
#pragma unroll
    for (int d = 1; d < 8; d <<= 1) mx = fmaxf(mx, __shfl_xor(mx, d, 64));
    float ex = expf(acc - mx), se = ex;
#pragma unroll
    for (int d = 1; d < 8; d <<= 1) se += __shfl_xor(se, d, 64);
    float v = acc - mx - logf(se);
    if (*flag) ((float*)Out)[(size_t)n * 8 + o] = v;
    else       ((u16*)Out)[(size_t)n * 8 + o] = f2bf(v);
}

// ---------------- launch ----------------
extern "C" void kernel_launch(void* const* d_in, const int* in_sizes, int n_in,
                              void* d_out, int out_size, void* d_ws, size_t ws_size,
                              hipStream_t stream) {
    const void* x   = d_in[0];
    const int* ei   = (const int*)d_in[1];
    const int N = in_sizes[0] / 128;
    const int E = in_sizes[1] / 2;
    const int* srcv = ei;
    const int* dstv = ei + E;
    const int NBUK = (N + 255) >> 8;         // buckets of 256 nodes
    const bool bucketed = (NBUK <= 256);
    const int chunk = (E + NCB - 1) / NCB;

    auto rnd = [](size_t b) { return (b + 255) & ~(size_t)255; };
    size_t need = rnd(256)                    // flag
                + rnd((size_t)N * 4)          // deg
                + rnd((size_t)(N + 1) * 4)    // rowptr
                + rnd(4096)                   // bsums
                + rnd(1024)                   // gcur
                + rnd(256 * NCB * 4)          // C matrix
                + rnd((size_t)E * 4)          // adj
                + 2 * rnd((size_t)N * 256)    // X, A
                + 4 * rnd(32768) + 2 * rnd(2048) + 2 * rnd(512) + rnd(64);
    if (ws_size < need) {
        k_sentinel<<<(out_size + 255) / 256, 256, 0, stream>>>((u16*)d_out, out_size);
        return;
    }

    char* p = (char*)d_ws;
    auto carve = [&](size_t bytes) { char* r = p; p += (bytes + 255) & ~(size_t)255; return r; };
    int* flag   = (int*)carve(256);
    int* deg    = (int*)carve((size_t)N * 4);
    int* rowptr = (int*)carve((size_t)(N + 1) * 4);
    int* bsums  = (int*)carve(4096);
    int* gcur   = (int*)carve(1024);
    int* C      = (int*)carve(256 * NCB * 4);
    int* adj    = (int*)carve((size_t)E * 4);
    u32* X      = (u32*)carve((size_t)N * 256);   // [N,128] packed bf16
    u32* A      = (u32*)carve((size_t)N * 256);   // agg buffer; dead until 1st aggregate
    u32* w1l = (u32*)carve(32768); u32* w1r = (u32*)carve(32768);
    u32* whl = (u32*)carve(32768); u32* whr = (u32*)carve(32768);
    u32* w2l = (u32*)carve(2048);  u32* w2r = (u32*)carve(2048);
    float* bf1 = (float*)carve(512); float* bfh = (float*)carve(512);
    float* bf2 = (float*)carve(64);
    u32* pairs = A;                  // consumed by k_fillb before first aggregate
    float* Y = (float*)A;            // layer-3 scratch in dead A
    float* R = Y + (size_t)N * 8;
    (void)n_in;

    k_detect<<<1, 64, 0, stream>>>((const u32*)x, flag);

    // canonicalize inputs
    k_cvt4<<<(N * 16 + 255) / 256, 256, 0, stream>>>(x, flag, (uint4*)X, N * 16);
    k_cvtp<<<134, 256, 0, stream>>>(d_in[3], d_in[5], d_in[6], d_in[8], d_in[9],
                                    d_in[11], d_in[4], d_in[7], d_in[10], flag,
                                    w1l, w1r, whl, whr, w2l, w2r, bf1, bfh, bf2);

    // CSR build
    hipMemsetAsync(deg, 0, (size_t)N * 4, stream);
    int nb = (N + 511) / 512;
    if (bucketed) {
        k_count<<<NCB, 256, 0, stream>>>(dstv, deg, C, E, N, chunk);
        k_scan1<<<nb, 512, 0, stream>>>(deg, rowptr, bsums, N);
        k_scan2<<<1, 128, 0, stream>>>(bsums, nb);
        k_scan3<<<nb, 512, 0, stream>>>(rowptr, bsums, gcur, N, E);
        k_scanC<<<NBUK, NCB, 0, stream>>>(C, gcur);
        k_place<<<NCB, 256, 0, stream>>>(srcv, dstv, C, pairs, E, N, chunk);
        k_fillb<<<NBUK, 256, 0, stream>>>(pairs, rowptr, deg, adj, E, N);
    } else {
        k_deg<<<(E + 255) / 256, 256, 0, stream>>>(dstv, deg, E, N);
        k_scan1<<<nb, 512, 0, stream>>>(deg, rowptr, bsums, N);
        k_scan2<<<1, 128, 0, stream>>>(bsums, nb);
        k_scan3<<<nb, 512, 0, stream>>>(rowptr, bsums, gcur, N, E);
        k_fill<<<(E + 255) / 256, 256, 0, stream>>>(srcv, dstv, rowptr, deg, adj, E, N);
    }

    int aggBlocks = (int)(((size_t)N * 64 + 255) / 256);
    int gemmBlocks = ((N + 15) / 16 + 3) / 4;
    int perNode8 = (int)(((size_t)N * 8 + 255) / 256);

    // L1: A=mean(X); h1=relu(A@W1l^T+b1+X@W1r^T) -> X (own-rows aliasing, safe)
    k_aggregate<<<aggBlocks, 256, 0, stream>>>((const uint4*)X, rowptr, adj, (uint4*)A, N, E);
    k_gemm128<0><<<gemmBlocks, 256, 0, stream>>>((const u16*)A, (const u16*)X, w1l, w1r, bf1, (u16*)X, N);
    // L2: A=mean(h1=X); h2=elu(A@Whl^T+bh+X@Whr^T) -> X
    k_aggregate<<<aggBlocks, 256, 0, stream>>>((const uint4*)X, rowptr, adj, (uint4*)A, N, E);
    k_gemm128<1><<<gemmBlocks, 256, 0, stream>>>((const u16*)A, (const u16*)X, whl, whr, bfh, (u16*)X, N);
    // L3 (linearity): y=h2@W2l^T, r=h2@W2r^T+b2; out = log_softmax(mean_agg(y)+r)
    k_lin8<<<perNode8, 256, 0, stream>>>((const u16*)X, w2l, w2r, bf2, Y, R, N);
    k_agg8sm<<<perNode8, 256, 0, stream>>>(Y, R, rowptr, adj, flag, d_out, N, E);
}

// Round 9
// 305.772 us; speedup vs baseline: 2.2979x; 1.0136x over previous
//
#include <hip/hip_runtime.h>

typedef unsigned int u32;
typedef unsigned short u16;
typedef short bf16x8 __attribute__((ext_vector_type(8)));   // 8 bf16 (4 VGPRs)
typedef float f32x4 __attribute__((ext_vector_type(4)));    // MFMA accumulator

#define NCB 256   // blocks for count/place passes

__device__ __forceinline__ float bf2f(u16 h) { return __uint_as_float(((u32)h) << 16); }
__device__ __forceinline__ u16 f2bf(float f) {
    u32 u = __float_as_uint(f);
    return (u16)((u + 0x7fffu + ((u >> 16) & 1u)) >> 16);   // RNE
}

// ---------------- diagnostic fallback: ws too small ----------------
__global__ __launch_bounds__(256) void k_sentinel(u16* out, int n) {
    int i = blockIdx.x * 256 + threadIdx.x;
    if (i < n) out[i] = f2bf(-7.0f);
}

// ---------------- dtype detection: flag=0 bf16-packed, flag=1 f32 ----------------
__global__ void k_detect(const u32* x, int* flag) {
    int lane = threadIdx.x;  // 64 threads
    int c = 0;
    for (int j = 0; j < 4; ++j) {
        u32 u = x[lane * 4 + j];
        u32 e = (u >> 7) & 0xffu;
        if ((e >= 0x30u && e <= 0x47u) || ((u & 0x7fffu) == 0u)) ++c;
    }
    for (int d = 32; d; d >>= 1) c += __shfl_down(c, d, 64);
    if (lane == 0) *flag = (c < 128) ? 1 : 0;
}

// ---------------- converters into canonical packed-bf16 / f32 ----------------
// vectorized: one uint4 (8 bf16) out per thread
__global__ __launch_bounds__(256) void k_cvt4(const void* src, const int* flag,
                                              uint4* dst, int n4) {
    int i = blockIdx.x * 256 + threadIdx.x;
    if (i >= n4) return;
    if (*flag) {
        const float4* s = (const float4*)src;
        float4 a = s[2 * i], b = s[2 * i + 1];
        uint4 o;
        o.x = (u32)f2bf(a.x) | ((u32)f2bf(a.y) << 16);
        o.y = (u32)f2bf(a.z) | ((u32)f2bf(a.w) << 16);
        o.z = (u32)f2bf(b.x) | ((u32)f2bf(b.y) << 16);
        o.w = (u32)f2bf(b.z) | ((u32)f2bf(b.w) << 16);
        dst[i] = o;
    } else {
        dst[i] = ((const uint4*)src)[i];
    }
}

// fused parameter conversion
__global__ __launch_bounds__(256) void k_cvtp(
    const void* s1l, const void* s1r, const void* shl, const void* shr,
    const void* s2l, const void* s2r, const void* sb1, const void* sbh,
    const void* sb2, const int* flag,
    u32* w1l, u32* w1r, u32* whl, u32* whr, u32* w2l, u32* w2r,
    float* bf1, float* bfh, float* bf2) {
    int b = blockIdx.x, t = threadIdx.x;
    int fl = *flag;
    auto cv = [&](const void* src, u32* dst, int base) {
        int i = base + t;
        if (fl) {
            const float* s = (const float*)src;
            dst[i] = (u32)f2bf(s[2 * i]) | ((u32)f2bf(s[2 * i + 1]) << 16);
        } else {
            dst[i] = ((const u32*)src)[i];
        }
    };
    auto cb = [&](const void* src, float* dst, int i) {
        dst[i] = fl ? ((const float*)src)[i] : bf2f(((const u16*)src)[i]);
    };
    if      (b <  32) cv(s1l, w1l, b * 256);
    else if (b <  64) cv(s1r, w1r, (b - 32) * 256);
    else if (b <  96) cv(shl, whl, (b - 64) * 256);
    else if (b < 128) cv(shr, whr, (b - 96) * 256);
    else if (b < 130) cv(s2l, w2l, (b - 128) * 256);
    else if (b < 132) cv(s2r, w2r, (b - 130) * 256);
    else if (b == 132) {
        if (t < 128) cb(sb1, bf1, t);
        else         cb(sbh, bfh, t - 128);
    } else {
        if (t < 8) cb(sb2, bf2, t);
    }
}

// ---------------- CSR build ----------------
__global__ __launch_bounds__(256) void k_count(const int* dstv, int* deg, int* C,
                                               int E, int N, int chunk) {
    __shared__ int hist[256];
    int t = threadIdx.x;
    hist[t] = 0;
    __syncthreads();
    int e0 = blockIdx.x * chunk;
    int e1 = min(e0 + chunk, E);
    for (int e = e0 + t; e < e1; e += 256) {
        int d = min(max(dstv[e], 0), N - 1);
        atomicAdd(&deg[d], 1);
        atomicAdd(&hist[d >> 8], 1);
    }
    __syncthreads();
    C[t * NCB + blockIdx.x] = hist[t];   // row t = bucket t (nbuk <= 256)
}

__global__ __launch_bounds__(512) void k_scan1(const int* deg, int* rowptr,
                                               int* bsums, int N) {
    __shared__ int sm[512];
    int i = blockIdx.x * 512 + threadIdx.x;
    int v = (i < N) ? deg[i] : 0;
    sm[threadIdx.x] = v;
    __syncthreads();
    for (int off = 1; off < 512; off <<= 1) {
        int t = (threadIdx.x >= off) ? sm[threadIdx.x - off] : 0;
        __syncthreads();
        sm[threadIdx.x] += t;
        __syncthreads();
    }
    if (i < N) rowptr[i] = sm[threadIdx.x] - v;            // exclusive
    if (threadIdx.x == 511) bsums[blockIdx.x] = sm[511];
}

__global__ __launch_bounds__(128) void k_scan2(int* bsums, int nb) {
    __shared__ int sm[128];
    int v = (threadIdx.x < nb) ? bsums[threadIdx.x] : 0;
    sm[threadIdx.x] = v;
    __syncthreads();
    for (int off = 1; off < 128; off <<= 1) {
        int t = (threadIdx.x >= off) ? sm[threadIdx.x - off] : 0;
        __syncthreads();
        sm[threadIdx.x] += t;
        __syncthreads();
    }
    if (threadIdx.x < nb) bsums[threadIdx.x] = sm[threadIdx.x] - v;  // exclusive
}

// finalize rowptr; sample bucket starts gcur[b] = rowptr[256*b]
__global__ __launch_bounds__(512) void k_scan3(int* rowptr, const int* bsums,
                                               int* gcur, int N, int E) {
    int i = blockIdx.x * 512 + threadIdx.x;
    if (i < N) {
        int v = rowptr[i] + bsums[blockIdx.x];
        rowptr[i] = v;
        if ((i & 255) == 0) gcur[i >> 8] = v;
    }
    if (i == 0) rowptr[N] = E;
}

__global__ __launch_bounds__(NCB) void k_scanC(int* C, const int* gcur) {
    __shared__ int sm[NCB];
    int b = blockIdx.x, t = threadIdx.x;
    int v = C[b * NCB + t];
    sm[t] = v;
    __syncthreads();
    for (int off = 1; off < NCB; off <<= 1) {
        int u = (t >= off) ? sm[t - off] : 0;
        __syncthreads();
        sm[t] += u;
        __syncthreads();
    }
    C[b * NCB + t] = sm[t] - v + gcur[b];
}

__global__ __launch_bounds__(256) void k_place(const int* srcv, const int* dstv,
                                               const int* C, u32* pairs,
                                               int E, int N, int chunk) {
    __shared__ int base[256], cnt[256];
    int t = threadIdx.x;
    base[t] = C[t * NCB + blockIdx.x];
    cnt[t] = 0;
    __syncthreads();
    int e0 = blockIdx.x * chunk;
    int e1 = min(e0 + chunk, E);
    for (int e = e0 + t; e < e1; e += 256) {
        int d = min(max(dstv[e], 0), N - 1);
        int s = min(max(srcv[e], 0), N - 1);
        int b = d >> 8;
        int pos = base[b] + atomicAdd(&cnt[b], 1);
        pos = min(max(pos, 0), E - 1);
        pairs[pos] = ((u32)s << 8) | (u32)(d & 255);
    }
}

__global__ __launch_bounds__(256) void k_fillb(const u32* pairs, const int* rowptr,
                                               const int* deg, int* adj, int E, int N) {
    int b = blockIdx.x;
    int n0 = b << 8;
    int nn = min(N - n0, 256);
    __shared__ int cur[256];
    int t = threadIdx.x;
    if (t < nn) cur[t] = deg[n0 + t];
    __syncthreads();
    int s0 = rowptr[n0];
    int s1 = rowptr[min(n0 + 256, N)];
    s0 = min(max(s0, 0), E);
    s1 = min(max(s1, s0), E);
    for (int e = s0 + t; e < s1; e += 256) {
        u32 pc = pairs[e];
        int ld = (int)(pc & 255u);
        ld = min(ld, nn - 1);
        int src = (int)(pc >> 8);
        int slot = atomicSub(&cur[ld], 1) - 1;
        int idx = rowptr[n0 + ld] + slot;
        idx = min(max(idx, 0), E - 1);
        adj[idx] = src;
    }
}

// fallback path for big N
__global__ __launch_bounds__(256) void k_deg(const int* dstv, int* deg, int E, int N) {
    int e = blockIdx.x * 256 + threadIdx.x;
    if (e >= E) return;
    int d = dstv[e]; d = min(max(d, 0), N - 1);
    atomicAdd(&deg[d], 1);
}

__global__ __launch_bounds__(256) void k_fill(const int* srcv, const int* dstv,
                                              const int* rowptr, int* deg,
                                              int* adj, int E, int N) {
    int e = blockIdx.x * 256 + threadIdx.x;
    if (e >= E) return;
    int d = dstv[e]; d = min(max(d, 0), N - 1);
    int slot = atomicSub(&deg[d], 1) - 1;
    int idx = rowptr[d] + slot;
    idx = min(max(idx, 0), E - 1);
    adj[idx] = srcv[e];
}

// ---------------- mean aggregation: one wave per node, 4x16-lane groups ----------
// Masked full-ILP: every group iteration issues 4 row loads unconditionally
// (indices past `end` clamp to adj[end-1], contribution masked by 0.0 via fmaf).
// All degrees run at 16 loads in flight per wave, not just deg>=16.
__device__ __forceinline__ void acc8m(uint4 u, float m, float* s) {
    const u32* pu = (const u32*)&u;
#pragma unroll
    for (int t = 0; t < 4; ++t) {
        s[2 * t]     = fmaf(__uint_as_float(pu[t] << 16), m, s[2 * t]);
        s[2 * t + 1] = fmaf(__uint_as_float(pu[t] & 0xffff0000u), m, s[2 * t + 1]);
    }
}

__global__ __launch_bounds__(256) void k_aggregate(const uint4* F, const int* rowptr,
                                                   const int* adj, uint4* A,
                                                   int N, int E) {
    int wid = (int)((blockIdx.x * 256u + threadIdx.x) >> 6);
    int lane = threadIdx.x & 63;
    if (wid >= N) return;
    int beg = rowptr[wid], end = rowptr[wid + 1];
    beg = min(max(beg, 0), E);
    end = min(max(end, beg), E);
    int g = lane >> 4, l = lane & 15;
    float s[8] = {0.f, 0.f, 0.f, 0.f, 0.f, 0.f, 0.f, 0.f};
    for (int j = beg + g; j < end; j += 16) {
        int i1 = j + 4, i2 = j + 8, i3 = j + 12;
        float m1 = (i1 < end) ? 1.f : 0.f;
        float m2 = (i2 < end) ? 1.f : 0.f;
        float m3 = (i3 < end) ? 1.f : 0.f;
        int a0 = min(max(adj[j], 0), N - 1);
        int a1 = min(max(adj[min(i1, end - 1)], 0), N - 1);
        int a2 = min(max(adj[min(i2, end - 1)], 0), N - 1);
        int a3 = min(max(adj[min(i3, end - 1)], 0), N - 1);
        uint4 u0 = F[(size_t)a0 * 16 + l];
        uint4 u1 = F[(size_t)a1 * 16 + l];
        uint4 u2 = F[(size_t)a2 * 16 + l];
        uint4 u3 = F[(size_t)a3 * 16 + l];
        acc8m(u0, 1.f, s);
        acc8m(u1, m1, s);
        acc8m(u2, m2, s);
        acc8m(u3, m3, s);
    }
#pragma unroll
    for (int k = 0; k < 8; ++k) {
        s[k] += __shfl_xor(s[k], 16, 64);
        s[k] += __shfl_xor(s[k], 32, 64);
    }
    if (g == 0) {
        float inv = 1.f / fmaxf((float)(end - beg), 1.f);
        uint4 r; u32* pr = (u32*)&r;
#pragma unroll
        for (int t = 0; t < 4; ++t)
            pr[t] = (u32)f2bf(s[2 * t] * inv) | ((u32)f2bf(s[2 * t + 1] * inv) << 16);
        A[(size_t)wid * 16 + l] = r;
    }
}

// ---------------- fused SAGE GEMM: h = act(Agg@Wl^T + b + Xin@Wr^T) ----------------
// W' = Wl||Wr staged in LDS in MFMA B-fragment order (64 KB); K-loop = 64
// ds_read_b128 + 64 MFMA per wave, no global B traffic.
template <int ACT>  // 0 = relu, 1 = elu
__global__ __launch_bounds__(256) void k_gemm128(const u16* Agg, const u16* Xin,
                                                 const u32* Wl, const u32* Wr,
                                                 const float* bias, u16* Out, int N) {
    __shared__ __align__(16) u16 Wsh[32768];   // 64 KB -> 2 blocks/CU
    int t = threadIdx.x;
#pragma unroll
    for (int i = 0; i < 16; ++i) {
        int f = i * 256 + t;
        int c = f >> 9, s = (f >> 6) & 7, q = (f >> 4) & 3, n = f & 15;
        int o = c * 16 + n;
        int k = s * 32 + q * 8;
        uint4 v;
        if (k < 128) v = *(const uint4*)(Wl + (size_t)o * 64 + (k >> 1));
        else         v = *(const uint4*)(Wr + (size_t)o * 64 + ((k - 128) >> 1));
        *(uint4*)(Wsh + f * 8) = v;
    }
    __syncthreads();

    int tile = blockIdx.x * 4 + (t >> 6);
    int lane = t & 63;
    int m0 = tile * 16;
    if (m0 >= N) return;
    int mrow = min(m0 + (lane & 15), N - 1);
    int kq = (lane >> 4) * 8;

    bf16x8 afrag[8];
#pragma unroll
    for (int s = 0; s < 8; ++s) {
        int k = s * 32 + kq;
        const u16* p = (k < 128) ? (Agg + (size_t)mrow * 128 + k)
                                 : (Xin + (size_t)mrow * 128 + (k - 128));
        afrag[s] = *(const bf16x8*)p;
    }

    f32x4 acc[8];
#pragma unroll
    for (int c = 0; c < 8; ++c) acc[c] = (f32x4){0.f, 0.f, 0.f, 0.f};

    const u16* lbase = Wsh + (lane >> 4) * 128 + (lane & 15) * 8;
#pragma unroll
    for (int c = 0; c < 8; ++c) {
#pragma unroll
        for (int s = 0; s < 8; ++s) {
            bf16x8 b = *(const bf16x8*)(lbase + (c * 8 + s) * 512);
            acc[c] = __builtin_amdgcn_mfma_f32_16x16x32_bf16(afrag[s], b, acc[c], 0, 0, 0);
        }
    }

#pragma unroll
    for (int c = 0; c < 8; ++c) {
        int o = c * 16 + (lane & 15);
        float bv = bias[o];
#pragma unroll
        for (int r = 0; r < 4; ++r) {
            int m = m0 + (lane >> 4) * 4 + r;
            float v = acc[c][r] + bv;
            v = (ACT == 0) ? fmaxf(v, 0.f) : ((v > 0.f) ? v : expm1f(v));
            if (m < N) Out[(size_t)m * 128 + o] = f2bf(v);
        }
    }
}

// ---------------- layer 3: y = h2@W2l^T, r = h2@W2r^T + b  (both [N,8] f32) -------
__device__ __forceinline__ float dot8(uint4 a, uint4 b, float acc) {
    const u32* pa = (const u32*)&a;
    const u32* pb = (const u32*)&b;
#pragma unroll
    for (int t = 0; t < 4; ++t) {
        acc = fmaf(__uint_as_float(pa[t] << 16), __uint_as_float(pb[t] << 16), acc);
        acc = fmaf(__uint_as_float(pa[t] & 0xffff0000u),
                   __uint_as_float(pb[t] & 0xffff0000u), acc);
    }
    return acc;
}

__global__ __launch_bounds__(256) void k_lin8(const u16* Xin, const u32* Wl,
                                              const u32* Wr, const float* bias,
                                              float* Y, float* R, int N) {
    int t = blockIdx.x * 256 + threadIdx.x;
    int n = t >> 3;
    int o = t & 7;
    if (n >= N) return;
    const uint4* xr = (const uint4*)(Xin + (size_t)n * 128);
    const uint4* wl = (const uint4*)(Wl + (size_t)o * 64);
    const uint4* wr = (const uint4*)(Wr + (size_t)o * 64);
    float al = 0.f, ar = bias[o];
#pragma unroll
    for (int i = 0; i < 16; ++i) {
        uint4 xv = xr[i];
        al = dot8(xv, wl[i], al);
        ar = dot8(xv, wr[i], ar);
    }
    Y[(size_t)n * 8 + o] = al;
    R[(size_t)n * 8 + o] = ar;
}

__global__ __launch_bounds__(256) void k_agg8sm(const float* Y, const float* R,
                                                const int* rowptr, const int* adj,
                                                const int* flag, void* Out,
                                                int N, int E) {
    int t = blockIdx.x * 256 + threadIdx.x;
    int n = t >> 3;
    int o = t & 7;
    if (n >= N) return;
    int beg = rowptr[n], end = rowptr[n + 1];
    beg = min(max(beg, 0), E);
    end = min(max(end, beg), E);
    float s = 0.f;
    int j = beg;
    for (; j + 1 < end; j += 2) {
        int a0 = min(max(adj[j], 0), N - 1);
        int a1 = min(max(adj[j + 1], 0), N - 1);
        s += Y[(size_t)a0 * 8 + o];
        s += Y[(size_t)a1 * 8 + o];
    }
    if (j < end) {
        int a0 = min(max(adj[j], 0), N - 1);
        s += Y[(size_t)a0 * 8 + o];
    }
    float acc = s / fmaxf((float)(end - beg), 1.f) + R[(size_t)n * 8 + o];
    float mx = acc;
#pragma unroll
    for (int d = 1; d < 8; d <<= 1) mx = fmaxf(mx, __shfl_xor(mx, d, 64));
    float ex = expf(acc - mx), se = ex;
#pragma unroll
    for (int d = 1; d < 8; d <<= 1) se += __shfl_xor(se, d, 64);
    float v = acc - mx - logf(se);
    if (*flag) ((float*)Out)[(size_t)n * 8 + o] = v;
    else       ((u16*)Out)[(size_t)n * 8 + o] = f2bf(v);
}

// ---------------- launch ----------------
extern "C" void kernel_launch(void* const* d_in, const int* in_sizes, int n_in,
                              void* d_out, int out_size, void* d_ws, size_t ws_size,
                              hipStream_t stream) {
    const void* x   = d_in[0];
    const int* ei   = (const int*)d_in[1];
    const int N = in_sizes[0] / 128;
    const int E = in_sizes[1] / 2;
    const int* srcv = ei;
    const int* dstv = ei + E;
    const int NBUK = (N + 255) >> 8;         // buckets of 256 nodes
    const bool bucketed = (NBUK <= 256);
    const int chunk = (E + NCB - 1) / NCB;

    auto rnd = [](size_t b) { return (b + 255) & ~(size_t)255; };
    size_t need = rnd(256)                    // flag
                + rnd((size_t)N * 4)          // deg
                + rnd((size_t)(N + 1) * 4)    // rowptr
                + rnd(4096)                   // bsums
                + rnd(1024)                   // gcur
                + rnd(256 * NCB * 4)          // C matrix
                + rnd((size_t)E * 4)          // adj
                + 2 * rnd((size_t)N * 256)    // X, A
                + 4 * rnd(32768) + 2 * rnd(2048) + 2 * rnd(512) + rnd(64);
    if (ws_size < need) {
        k_sentinel<<<(out_size + 255) / 256, 256, 0, stream>>>((u16*)d_out, out_size);
        return;
    }

    char* p = (char*)d_ws;
    auto carve = [&](size_t bytes) { char* r = p; p += (bytes + 255) & ~(size_t)255; return r; };
    int* flag   = (int*)carve(256);
    int* deg    = (int*)carve((size_t)N * 4);
    int* rowptr = (int*)carve((size_t)(N + 1) * 4);
    int* bsums  = (int*)carve(4096);
    int* gcur   = (int*)carve(1024);
    int* C      = (int*)carve(256 * NCB * 4);
    int* adj    = (int*)carve((size_t)E * 4);
    u32* X      = (u32*)carve((size_t)N * 256);   // [N,128] packed bf16
    u32* A      = (u32*)carve((size_t)N * 256);   // agg buffer; dead until 1st aggregate
    u32* w1l = (u32*)carve(32768); u32* w1r = (u32*)carve(32768);
    u32* whl = (u32*)carve(32768); u32* whr = (u32*)carve(32768);
    u32* w2l = (u32*)carve(2048);  u32* w2r = (u32*)carve(2048);
    float* bf1 = (float*)carve(512); float* bfh = (float*)carve(512);
    float* bf2 = (float*)carve(64);
    u32* pairs = A;                  // consumed by k_fillb before first aggregate
    float* Y = (float*)A;            // layer-3 scratch in dead A
    float* R = Y + (size_t)N * 8;
    (void)n_in;

    k_detect<<<1, 64, 0, stream>>>((const u32*)x, flag);

    // canonicalize inputs
    k_cvt4<<<(N * 16 + 255) / 256, 256, 0, stream>>>(x, flag, (uint4*)X, N * 16);
    k_cvtp<<<134, 256, 0, stream>>>(d_in[3], d_in[5], d_in[6], d_in[8], d_in[9],
                                    d_in[11], d_in[4], d_in[7], d_in[10], flag,
                                    w1l, w1r, whl, whr, w2l, w2r, bf1, bfh, bf2);

    // CSR build
    hipMemsetAsync(deg, 0, (size_t)N * 4, stream);
    int nb = (N + 511) / 512;
    if (bucketed) {
        k_count<<<NCB, 256, 0, stream>>>(dstv, deg, C, E, N, chunk);
        k_scan1<<<nb, 512, 0, stream>>>(deg, rowptr, bsums, N);
        k_scan2<<<1, 128, 0, stream>>>(bsums, nb);
        k_scan3<<<nb, 512, 0, stream>>>(rowptr, bsums, gcur, N, E);
        k_scanC<<<NBUK, NCB, 0, stream>>>(C, gcur);
        k_place<<<NCB, 256, 0, stream>>>(srcv, dstv, C, pairs, E, N, chunk);
        k_fillb<<<NBUK, 256, 0, stream>>>(pairs, rowptr, deg, adj, E, N);
    } else {
        k_deg<<<(E + 255) / 256, 256, 0, stream>>>(dstv, deg, E, N);
        k_scan1<<<nb, 512, 0, stream>>>(deg, rowptr, bsums, N);
        k_scan2<<<1, 128, 0, stream>>>(bsums, nb);
        k_scan3<<<nb, 512, 0, stream>>>(rowptr, bsums, gcur, N, E);
        k_fill<<<(E + 255) / 256, 256, 0, stream>>>(srcv, dstv, rowptr, deg, adj, E, N);
    }

    int aggBlocks = (int)(((size_t)N * 64 + 255) / 256);
    int gemmBlocks = ((N + 15) / 16 + 3) / 4;
    int perNode8 = (int)(((size_t)N * 8 + 255) / 256);

    // L1: A=mean(X); h1=relu(A@W1l^T+b1+X@W1r^T) -> X (own-rows aliasing, safe)
    k_aggregate<<<aggBlocks, 256, 0, stream>>>((const uint4*)X, rowptr, adj, (uint4*)A, N, E);
    k_gemm128<0><<<gemmBlocks, 256, 0, stream>>>((const u16*)A, (const u16*)X, w1l, w1r, bf1, (u16*)X, N);
    // L2: A=mean(h1=X); h2=elu(A@Whl^T+bh+X@Whr^T) -> X
    k_aggregate<<<aggBlocks, 256, 0, stream>>>((const uint4*)X, rowptr, adj, (uint4*)A, N, E);
    k_gemm128<1><<<gemmBlocks, 256, 0, stream>>>((const u16*)A, (const u16*)X, whl, whr, bfh, (u16*)X, N);
    // L3 (linearity): y=h2@W2l^T, r=h2@W2r^T+b2; out = log_softmax(mean_agg(y)+r)
    k_lin8<<<perNode8, 256, 0, stream>>>((const u16*)X, w2l, w2r, bf2, Y, R, N);
    k_agg8sm<<<perNode8, 256, 0, stream>>>(Y, R, rowptr, adj, flag, d_out, N, E);
}

// Round 10
// 296.540 us; speedup vs baseline: 2.3694x; 1.0311x over previous
//
#include <hip/hip_runtime.h>

typedef unsigned int u32;
typedef unsigned short u16;
typedef short bf16x8 __attribute__((ext_vector_type(8)));   // 8 bf16 (4 VGPRs)
typedef float f32x4 __attribute__((ext_vector_type(4)));    // MFMA accumulator

#define NCB 256   // blocks for count/place passes (fixed)

__device__ __forceinline__ float bf2f(u16 h) { return __uint_as_float(((u32)h) << 16); }
__device__ __forceinline__ u16 f2bf(float f) {
    u32 u = __float_as_uint(f);
    return (u16)((u + 0x7fffu + ((u >> 16) & 1u)) >> 16);   // RNE
}

// ---------------- diagnostic fallback: ws too small ----------------
__global__ __launch_bounds__(256) void k_sentinel(u16* out, int n) {
    int i = blockIdx.x * 256 + threadIdx.x;
    if (i < n) out[i] = f2bf(-7.0f);
}

// ---------------- init: zero deg + dtype-detect (flag=0 bf16, 1 f32) --------------
__global__ __launch_bounds__(256) void k_init(const u32* x, int* flag, int* deg, int N) {
    int i = blockIdx.x * 256 + threadIdx.x;
    if (i < N) deg[i] = 0;
    if (blockIdx.x == 0 && threadIdx.x < 64) {
        int lane = threadIdx.x;
        int c = 0;
        for (int j = 0; j < 4; ++j) {
            u32 u = x[lane * 4 + j];
            u32 e = (u >> 7) & 0xffu;
            if ((e >= 0x30u && e <= 0x47u) || ((u & 0x7fffu) == 0u)) ++c;
        }
        for (int d = 32; d; d >>= 1) c += __shfl_down(c, d, 64);
        if (lane == 0) *flag = (c < 128) ? 1 : 0;
    }
}

// ---------------- front: x-convert + param-convert + degree/bucket count ----------
// roles by blockIdx: [0,cvtB) cvt4 | [cvtB,cvtB+134) cvtp | [cvtB+134,cvtB+134+256) count
__global__ __launch_bounds__(256) void k_front(
    const void* x, const int* dstv, const int* flag, int bucketed,
    uint4* X, int* deg, int* C, int E, int N, int chunk, int cvtB,
    const void* s1l, const void* s1r, const void* shl, const void* shr,
    const void* s2l, const void* s2r, const void* sb1, const void* sbh,
    const void* sb2,
    u32* w1l, u32* w1r, u32* whl, u32* whr, u32* w2l, u32* w2r,
    float* bf1, float* bfh, float* bf2) {
    __shared__ int hist[256];
    int b = blockIdx.x, t = threadIdx.x;
    if (b < cvtB) {
        int i = b * 256 + t;
        if (i >= N * 16) return;
        if (*flag) {
            const float4* s = (const float4*)x;
            float4 a = s[2 * i], c4 = s[2 * i + 1];
            uint4 o;
            o.x = (u32)f2bf(a.x) | ((u32)f2bf(a.y) << 16);
            o.y = (u32)f2bf(a.z) | ((u32)f2bf(a.w) << 16);
            o.z = (u32)f2bf(c4.x) | ((u32)f2bf(c4.y) << 16);
            o.w = (u32)f2bf(c4.z) | ((u32)f2bf(c4.w) << 16);
            X[i] = o;
        } else {
            X[i] = ((const uint4*)x)[i];
        }
    } else if (b < cvtB + 134) {
        int bb = b - cvtB;
        int fl = *flag;
        auto cv = [&](const void* src, u32* dst, int base) {
            int i = base + t;
            if (fl) {
                const float* s = (const float*)src;
                dst[i] = (u32)f2bf(s[2 * i]) | ((u32)f2bf(s[2 * i + 1]) << 16);
            } else {
                dst[i] = ((const u32*)src)[i];
            }
        };
        auto cb = [&](const void* src, float* dst, int i) {
            dst[i] = fl ? ((const float*)src)[i] : bf2f(((const u16*)src)[i]);
        };
        if      (bb <  32) cv(s1l, w1l, bb * 256);
        else if (bb <  64) cv(s1r, w1r, (bb - 32) * 256);
        else if (bb <  96) cv(shl, whl, (bb - 64) * 256);
        else if (bb < 128) cv(shr, whr, (bb - 96) * 256);
        else if (bb < 130) cv(s2l, w2l, (bb - 128) * 256);
        else if (bb < 132) cv(s2r, w2r, (bb - 130) * 256);
        else if (bb == 132) {
            if (t < 128) cb(sb1, bf1, t);
            else         cb(sbh, bfh, t - 128);
        } else {
            if (t < 8) cb(sb2, bf2, t);
        }
    } else {
        int cb2 = b - cvtB - 134;    // count block 0..255
        hist[t] = 0;
        __syncthreads();
        int e0 = cb2 * chunk;
        int e1 = min(e0 + chunk, E);
        for (int e = e0 + t; e < e1; e += 256) {
            int d = min(max(dstv[e], 0), N - 1);
            atomicAdd(&deg[d], 1);
            if (bucketed) atomicAdd(&hist[d >> 8], 1);
        }
        if (bucketed) {
            __syncthreads();
            C[cb2 * 256 + t] = hist[t];   // transposed: coalesced write
        }
    }
}

// ---------------- scan 1: local-exclusive prefix (r0) + block sums ----------------
__global__ __launch_bounds__(512) void k_scan1(const int* deg, int* r0,
                                               int* bsums, int N) {
    __shared__ int sm[512];
    int i = blockIdx.x * 512 + threadIdx.x;
    int v = (i < N) ? deg[i] : 0;
    sm[threadIdx.x] = v;
    __syncthreads();
    for (int off = 1; off < 512; off <<= 1) {
        int t = (threadIdx.x >= off) ? sm[threadIdx.x - off] : 0;
        __syncthreads();
        sm[threadIdx.x] += t;
        __syncthreads();
    }
    if (i < N) r0[i] = sm[threadIdx.x] - v;            // exclusive within block
    if (threadIdx.x == 511) bsums[blockIdx.x] = sm[511];
}

// ---------------- scan 3C: finalize rowptr (type A) + bucket C-scan (type B) ------
// Every block redundantly scans bsums (nbA <= 128) in LDS. Type A blocks
// (b < nbA) finalize rowptr. Type B blocks (one per bucket) compute gcur from
// r0+bsums (r0 is read-only here: no race) and exclusive-scan their C column.
__global__ __launch_bounds__(512) void k_scan3C(const int* r0, const int* bsums,
                                                int* rowptr, int* C, int N, int E,
                                                int nbA, int nbuk) {
    __shared__ int sb[128];
    __shared__ int sc[256];
    int b = blockIdx.x, t = threadIdx.x;
    if (t < 128) sb[t] = (t < nbA) ? bsums[t] : 0;
    __syncthreads();
    for (int off = 1; off < 128; off <<= 1) {
        int u = (t < 128 && t >= off) ? sb[t - off] : 0;
        __syncthreads();
        if (t < 128) sb[t] += u;
        __syncthreads();
    }
    // sb[k] = inclusive sum; exclusive prefix of block k = (k ? sb[k-1] : 0)
    if (b < nbA) {
        int i = b * 512 + t;
        int pre = (b > 0) ? sb[b - 1] : 0;
        if (i < N) rowptr[i] = r0[i] + pre;
        if (i == 0) rowptr[N] = E;
    } else {
        int bu = b - nbA;                 // bucket id
        int n0 = bu << 8;
        int s1 = n0 >> 9;                 // scan1 block containing n0
        int gcur = r0[n0] + ((s1 > 0) ? sb[s1 - 1] : 0);
        int vv = 0;
        if (t < 256) { vv = C[t * 256 + bu]; sc[t] = vv; }
        __syncthreads();
        for (int off = 1; off < 256; off <<= 1) {
            int u = (t < 256 && t >= off) ? sc[t - off] : 0;
            __syncthreads();
            if (t < 256) sc[t] += u;
            __syncthreads();
        }
        if (t < 256) C[t * 256 + bu] = sc[t] - vv + gcur;   // excl + bucket base
    }
}

// ---------------- place edges into bucket-segmented pairs ----------------
__global__ __launch_bounds__(256) void k_place(const int* srcv, const int* dstv,
                                               const int* C, u32* pairs,
                                               int E, int N, int chunk) {
    __shared__ int base[256], cnt[256];
    int t = threadIdx.x;
    base[t] = C[blockIdx.x * 256 + t];
    cnt[t] = 0;
    __syncthreads();
    int e0 = blockIdx.x * chunk;
    int e1 = min(e0 + chunk, E);
    for (int e = e0 + t; e < e1; e += 256) {
        int d = min(max(dstv[e], 0), N - 1);
        int s = min(max(srcv[e], 0), N - 1);
        int b = d >> 8;
        int pos = base[b] + atomicAdd(&cnt[b], 1);
        pos = min(max(pos, 0), E - 1);
        pairs[pos] = ((u32)s << 8) | (u32)(d & 255);
    }
}

// one block per bucket; LDS countdown cursors; XCD-exclusive adj window
__global__ __launch_bounds__(256) void k_fillb(const u32* pairs, const int* rowptr,
                                               const int* deg, int* adj, int E, int N) {
    int b = blockIdx.x;
    int n0 = b << 8;
    int nn = min(N - n0, 256);
    __shared__ int cur[256];
    int t = threadIdx.x;
    if (t < nn) cur[t] = deg[n0 + t];
    __syncthreads();
    int s0 = rowptr[n0];
    int s1 = rowptr[min(n0 + 256, N)];
    s0 = min(max(s0, 0), E);
    s1 = min(max(s1, s0), E);
    for (int e = s0 + t; e < s1; e += 256) {
        u32 pc = pairs[e];
        int ld = (int)(pc & 255u);
        ld = min(ld, nn - 1);
        int src = (int)(pc >> 8);
        int slot = atomicSub(&cur[ld], 1) - 1;
        int idx = rowptr[n0 + ld] + slot;
        idx = min(max(idx, 0), E - 1);
        adj[idx] = src;
    }
}

// fallback for big N: direct scatter (destroys deg as countdown cursor)
__global__ __launch_bounds__(256) void k_fill(const int* srcv, const int* dstv,
                                              const int* rowptr, int* deg,
                                              int* adj, int E, int N) {
    int e = blockIdx.x * 256 + threadIdx.x;
    if (e >= E) return;
    int d = dstv[e]; d = min(max(d, 0), N - 1);
    int slot = atomicSub(&deg[d], 1) - 1;
    int idx = rowptr[d] + slot;
    idx = min(max(idx, 0), E - 1);
    adj[idx] = srcv[e];
}

// ---------------- mean aggregation: one wave per node, masked full-ILP -----------
__device__ __forceinline__ void acc8m(uint4 u, float m, float* s) {
    const u32* pu = (const u32*)&u;
#pragma unroll
    for (int t = 0; t < 4; ++t) {
        s[2 * t]     = fmaf(__uint_as_float(pu[t] << 16), m, s[2 * t]);
        s[2 * t + 1] = fmaf(__uint_as_float(pu[t] & 0xffff0000u), m, s[2 * t + 1]);
    }
}

__global__ __launch_bounds__(256) void k_aggregate(const uint4* F, const int* rowptr,
                                                   const int* adj, uint4* A,
                                                   int N, int E) {
    int wid = (int)((blockIdx.x * 256u + threadIdx.x) >> 6);
    int lane = threadIdx.x & 63;
    if (wid >= N) return;
    int beg = rowptr[wid], end = rowptr[wid + 1];
    beg = min(max(beg, 0), E);
    end = min(max(end, beg), E);
    int g = lane >> 4, l = lane & 15;
    float s[8] = {0.f, 0.f, 0.f, 0.f, 0.f, 0.f, 0.f, 0.f};
    for (int j = beg + g; j < end; j += 16) {
        int i1 = j + 4, i2 = j + 8, i3 = j + 12;
        float m1 = (i1 < end) ? 1.f : 0.f;
        float m2 = (i2 < end) ? 1.f : 0.f;
        float m3 = (i3 < end) ? 1.f : 0.f;
        int a0 = min(max(adj[j], 0), N - 1);
        int a1 = min(max(adj[min(i1, end - 1)], 0), N - 1);
        int a2 = min(max(adj[min(i2, end - 1)], 0), N - 1);
        int a3 = min(max(adj[min(i3, end - 1)], 0), N - 1);
        uint4 u0 = F[(size_t)a0 * 16 + l];
        uint4 u1 = F[(size_t)a1 * 16 + l];
        uint4 u2 = F[(size_t)a2 * 16 + l];
        uint4 u3 = F[(size_t)a3 * 16 + l];
        acc8m(u0, 1.f, s);
        acc8m(u1, m1, s);
        acc8m(u2, m2, s);
        acc8m(u3, m3, s);
    }
#pragma unroll
    for (int k = 0; k < 8; ++k) {
        s[k] += __shfl_xor(s[k], 16, 64);
        s[k] += __shfl_xor(s[k], 32, 64);
    }
    if (g == 0) {
        float inv = 1.f / fmaxf((float)(end - beg), 1.f);
        uint4 r; u32* pr = (u32*)&r;
#pragma unroll
        for (int t = 0; t < 4; ++t)
            pr[t] = (u32)f2bf(s[2 * t] * inv) | ((u32)f2bf(s[2 * t + 1] * inv) << 16);
        A[(size_t)wid * 16 + l] = r;
    }
}

// ---------------- layer-1 GEMM: h1 = relu(Agg@Wl^T + b + Xin@Wr^T) ----------------
// W' = Wl||Wr staged in LDS in MFMA B-fragment order (64 KB).
__global__ __launch_bounds__(256) void k_gemm128(const u16* Agg, const u16* Xin,
                                                 const u32* Wl, const u32* Wr,
                                                 const float* bias, u16* Out, int N) {
    __shared__ __align__(16) u16 Wsh[32768];   // 64 KB -> 2 blocks/CU
    int t = threadIdx.x;
#pragma unroll
    for (int i = 0; i < 16; ++i) {
        int f = i * 256 + t;
        int c = f >> 9, s = (f >> 6) & 7, q = (f >> 4) & 3, n = f & 15;
        int o = c * 16 + n;
        int k = s * 32 + q * 8;
        uint4 v;
        if (k < 128) v = *(const uint4*)(Wl + (size_t)o * 64 + (k >> 1));
        else         v = *(const uint4*)(Wr + (size_t)o * 64 + ((k - 128) >> 1));
        *(uint4*)(Wsh + f * 8) = v;
    }
    __syncthreads();

    int tile = blockIdx.x * 4 + (t >> 6);
    int lane = t & 63;
    int m0 = tile * 16;
    if (m0 >= N) return;
    int mrow = min(m0 + (lane & 15), N - 1);
    int kq = (lane >> 4) * 8;

    bf16x8 afrag[8];
#pragma unroll
    for (int s = 0; s < 8; ++s) {
        int k = s * 32 + kq;
        const u16* p = (k < 128) ? (Agg + (size_t)mrow * 128 + k)
                                 : (Xin + (size_t)mrow * 128 + (k - 128));
        afrag[s] = *(const bf16x8*)p;
    }

    f32x4 acc[8];
#pragma unroll
    for (int c = 0; c < 8; ++c) acc[c] = (f32x4){0.f, 0.f, 0.f, 0.f};

    const u16* lbase = Wsh + (lane >> 4) * 128 + (lane & 15) * 8;
#pragma unroll
    for (int c = 0; c < 8; ++c) {
#pragma unroll
        for (int s = 0; s < 8; ++s) {
            bf16x8 b = *(const bf16x8*)(lbase + (c * 8 + s) * 512);
            acc[c] = __builtin_amdgcn_mfma_f32_16x16x32_bf16(afrag[s], b, acc[c], 0, 0, 0);
        }
    }

#pragma unroll
    for (int c = 0; c < 8; ++c) {
        int o = c * 16 + (lane & 15);
        float bv = bias[o];
#pragma unroll
        for (int r = 0; r < 4; ++r) {
            int m = m0 + (lane >> 4) * 4 + r;
            float v = acc[c][r] + bv;
            v = fmaxf(v, 0.f);   // relu
            if (m < N) Out[(size_t)m * 128 + o] = f2bf(v);
        }
    }
}

// ---------------- layer-2 GEMM + elu + fused layer-3 head ------------------------
// h2 stays in registers (C-layout row=quad*4+r, col=c*16+k15). Head computes
// Y = h2@W2l^T, R = h2@W2r^T + b2 via in-quad shfl_xor reductions; h2 never
// touches global memory.
__global__ __launch_bounds__(256) void k_gemm2(const u16* Agg, const u16* Xin,
                                               const u32* Wl, const u32* Wr,
                                               const float* bias,
                                               const u32* W2l, const u32* W2r,
                                               const float* b2,
                                               float* Y, float* R, int N) {
    __shared__ __align__(16) u16 Wsh[32768];   // 64 KB
    __shared__ float W2sh[2048];               // +8 KB: W2l,W2r as f32
    int t = threadIdx.x;
#pragma unroll
    for (int i = 0; i < 16; ++i) {
        int f = i * 256 + t;
        int c = f >> 9, s = (f >> 6) & 7, q = (f >> 4) & 3, n = f & 15;
        int o = c * 16 + n;
        int k = s * 32 + q * 8;
        uint4 v;
        if (k < 128) v = *(const uint4*)(Wl + (size_t)o * 64 + (k >> 1));
        else         v = *(const uint4*)(Wr + (size_t)o * 64 + ((k - 128) >> 1));
        *(uint4*)(Wsh + f * 8) = v;
    }
#pragma unroll
    for (int i = t; i < 512; i += 256) {
        u32 wa = W2l[i], wb = W2r[i];
        W2sh[2 * i]            = bf2f((u16)(wa & 0xffffu));
        W2sh[2 * i + 1]        = bf2f((u16)(wa >> 16));
        W2sh[1024 + 2 * i]     = bf2f((u16)(wb & 0xffffu));
        W2sh[1024 + 2 * i + 1] = bf2f((u16)(wb >> 16));
    }
    __syncthreads();

    int tile = blockIdx.x * 4 + (t >> 6);
    int lane = t & 63;
    int m0 = tile * 16;
    if (m0 >= N) return;
    int mrow = min(m0 + (lane & 15), N - 1);
    int kq = (lane >> 4) * 8;

    bf16x8 afrag[8];
#pragma unroll
    for (int s = 0; s < 8; ++s) {
        int k = s * 32 + kq;
        const u16* p = (k < 128) ? (Agg + (size_t)mrow * 128 + k)
                                 : (Xin + (size_t)mrow * 128 + (k - 128));
        afrag[s] = *(const bf16x8*)p;
    }

    f32x4 acc[8];
#pragma unroll
    for (int c = 0; c < 8; ++c) acc[c] = (f32x4){0.f, 0.f, 0.f, 0.f};

    const u16* lbase = Wsh + (lane >> 4) * 128 + (lane & 15) * 8;
#pragma unroll
    for (int c = 0; c < 8; ++c) {
#pragma unroll
        for (int s = 0; s < 8; ++s) {
            bf16x8 b = *(const bf16x8*)(lbase + (c * 8 + s) * 512);
            acc[c] = __builtin_amdgcn_mfma_f32_16x16x32_bf16(afrag[s], b, acc[c], 0, 0, 0);
        }
    }

    int quad = lane >> 4, k15 = lane & 15;
    // elu in-place: acc[c][r] = h2[m0+quad*4+r][c*16+k15]
#pragma unroll
    for (int c = 0; c < 8; ++c) {
        float bv = bias[c * 16 + k15];
#pragma unroll
        for (int r = 0; r < 4; ++r) {
            float v = acc[c][r] + bv;
            acc[c][r] = (v > 0.f) ? v : expm1f(v);
        }
    }
    // head: per output j, per row r: partial over c, reduce over 16 lanes of quad
#pragma unroll
    for (int j = 0; j < 8; ++j) {
        float py[4] = {0.f, 0.f, 0.f, 0.f};
        float pr[4] = {0.f, 0.f, 0.f, 0.f};
#pragma unroll
        for (int c = 0; c < 8; ++c) {
            float w1 = W2sh[j * 128 + c * 16 + k15];
            float w2 = W2sh[1024 + j * 128 + c * 16 + k15];
#pragma unroll
            for (int r = 0; r < 4; ++r) {
                py[r] = fmaf(acc[c][r], w1, py[r]);
                pr[r] = fmaf(acc[c][r], w2, pr[r]);
            }
        }
#pragma unroll
        for (int r = 0; r < 4; ++r) {
#pragma unroll
            for (int d = 1; d < 16; d <<= 1) {
                py[r] += __shfl_xor(py[r], d, 64);
                pr[r] += __shfl_xor(pr[r], d, 64);
            }
            int m = m0 + quad * 4 + r;
            if (k15 == j && m < N) {
                Y[(size_t)m * 8 + j] = py[r];
                R[(size_t)m * 8 + j] = pr[r] + b2[j];
            }
        }
    }
}

// ---------------- final: mean-aggregate Y + R + log_softmax ----------------------
__global__ __launch_bounds__(256) void k_agg8sm(const float* Y, const float* R,
                                                const int* rowptr, const int* adj,
                                                const int* flag, void* Out,
                                                int N, int E) {
    int t = blockIdx.x * 256 + threadIdx.x;
    int n = t >> 3;
    int o = t & 7;
    if (n >= N) return;
    int beg = rowptr[n], end = rowptr[n + 1];
    beg = min(max(beg, 0), E);
    end = min(max(end, beg), E);
    float s = 0.f;
    int j = beg;
    for (; j + 1 < end; j += 2) {
        int a0 = min(max(adj[j], 0), N - 1);
        int a1 = min(max(adj[j + 1], 0), N - 1);
        s += Y[(size_t)a0 * 8 + o];
        s += Y[(size_t)a1 * 8 + o];
    }
    if (j < end) {
        int a0 = min(max(adj[j], 0), N - 1);
        s += Y[(size_t)a0 * 8 + o];
    }
    float acc = s / fmaxf((float)(end - beg), 1.f) + R[(size_t)n * 8 + o];
    float mx = acc;
#pragma unroll
    for (int d = 1; d < 8; d <<= 1) mx = fmaxf(mx, __shfl_xor(mx, d, 64));
    float ex = expf(acc - mx), se = ex;
#pragma unroll
    for (int d = 1; d < 8; d <<= 1) se += __shfl_xor(se, d, 64);
    float v = acc - mx - logf(se);
    if (*flag) ((float*)Out)[(size_t)n * 8 + o] = v;
    else       ((u16*)Out)[(size_t)n * 8 + o] = f2bf(v);
}

// ---------------- launch ----------------
extern "C" void kernel_launch(void* const* d_in, const int* in_sizes, int n_in,
                              void* d_out, int out_size, void* d_ws, size_t ws_size,
                              hipStream_t stream) {
    const void* x   = d_in[0];
    const int* ei   = (const int*)d_in[1];
    const int N = in_sizes[0] / 128;
    const int E = in_sizes[1] / 2;
    const int* srcv = ei;
    const int* dstv = ei + E;
    const int NBUK = (N + 255) >> 8;         // buckets of 256 nodes
    const int bucketed = (NBUK <= 256) ? 1 : 0;
    const int chunk = (E + NCB - 1) / NCB;
    const int cvtB = (N * 16 + 255) / 256;
    const int nbA = (N + 511) / 512;

    auto rnd = [](size_t b) { return (b + 255) & ~(size_t)255; };
    size_t need = rnd(256)                    // flag
                + rnd((size_t)N * 4)          // deg
                + rnd((size_t)N * 4)          // r0
                + rnd((size_t)(N + 1) * 4)    // rowptr
                + rnd(4096)                   // bsums
                + rnd(256 * NCB * 4)          // C matrix
                + rnd((size_t)E * 4)          // adj
                + 2 * rnd((size_t)N * 256)    // X, A
                + 2 * rnd((size_t)N * 32)     // Y, R
                + 4 * rnd(32768) + 2 * rnd(2048) + 2 * rnd(512) + rnd(64);
    if (ws_size < need) {
        k_sentinel<<<(out_size + 255) / 256, 256, 0, stream>>>((u16*)d_out, out_size);
        return;
    }

    char* p = (char*)d_ws;
    auto carve = [&](size_t bytes) { char* r = p; p += (bytes + 255) & ~(size_t)255; return r; };
    int* flag   = (int*)carve(256);
    int* deg    = (int*)carve((size_t)N * 4);
    int* r0     = (int*)carve((size_t)N * 4);
    int* rowptr = (int*)carve((size_t)(N + 1) * 4);
    int* bsums  = (int*)carve(4096);
    int* C      = (int*)carve(256 * NCB * 4);
    int* adj    = (int*)carve((size_t)E * 4);
    u32* X      = (u32*)carve((size_t)N * 256);   // [N,128] packed bf16
    u32* A      = (u32*)carve((size_t)N * 256);   // agg buffer
    float* Y    = (float*)carve((size_t)N * 32);  // [N,8] f32
    float* R    = (float*)carve((size_t)N * 32);
    u32* w1l = (u32*)carve(32768); u32* w1r = (u32*)carve(32768);
    u32* whl = (u32*)carve(32768); u32* whr = (u32*)carve(32768);
    u32* w2l = (u32*)carve(2048);  u32* w2r = (u32*)carve(2048);
    float* bf1 = (float*)carve(512); float* bfh = (float*)carve(512);
    float* bf2 = (float*)carve(64);
    u32* pairs = A;                  // consumed by k_fillb before first aggregate
    (void)n_in;

    // 1: zero deg + dtype detect
    k_init<<<(N + 255) / 256, 256, 0, stream>>>((const u32*)x, flag, deg, N);
    // 2: convert x + params, degree/bucket count
    k_front<<<cvtB + 134 + 256, 256, 0, stream>>>(
        x, dstv, flag, bucketed, (uint4*)X, deg, C, E, N, chunk, cvtB,
        d_in[3], d_in[5], d_in[6], d_in[8], d_in[9], d_in[11],
        d_in[4], d_in[7], d_in[10],
        w1l, w1r, whl, whr, w2l, w2r, bf1, bfh, bf2);
    // 3-4: scans
    k_scan1<<<nbA, 512, 0, stream>>>(deg, r0, bsums, N);
    k_scan3C<<<nbA + (bucketed ? NBUK : 0), 512, 0, stream>>>(
        r0, bsums, rowptr, C, N, E, nbA, bucketed ? NBUK : 0);
    // 5-6: adjacency fill
    if (bucketed) {
        k_place<<<NCB, 256, 0, stream>>>(srcv, dstv, C, pairs, E, N, chunk);
        k_fillb<<<NBUK, 256, 0, stream>>>(pairs, rowptr, deg, adj, E, N);
    } else {
        k_fill<<<(E + 255) / 256, 256, 0, stream>>>(srcv, dstv, rowptr, deg, adj, E, N);
    }

    int aggBlocks = (int)(((size_t)N * 64 + 255) / 256);
    int gemmBlocks = ((N + 15) / 16 + 3) / 4;
    int perNode8 = (int)(((size_t)N * 8 + 255) / 256);

    // 7-8: L1  A=mean(X); h1=relu(A@W1l^T+b1+X@W1r^T) -> X (own-rows aliasing)
    k_aggregate<<<aggBlocks, 256, 0, stream>>>((const uint4*)X, rowptr, adj, (uint4*)A, N, E);
    k_gemm128<<<gemmBlocks, 256, 0, stream>>>((const u16*)A, (const u16*)X, w1l, w1r, bf1, (u16*)X, N);
    // 9-10: L2 A=mean(h1); fused gemm2+elu+head -> Y,R (h2 never materialized)
    k_aggregate<<<aggBlocks, 256, 0, stream>>>((const uint4*)X, rowptr, adj, (uint4*)A, N, E);
    k_gemm2<<<gemmBlocks, 256, 0, stream>>>((const u16*)A, (const u16*)X, whl, whr, bfh,
                                            w2l, w2r, bf2, Y, R, N);
    // 11: out = log_softmax(mean_agg(Y) + R)
    k_agg8sm<<<perNode8, 256, 0, stream>>>(Y, R, rowptr, adj, flag, d_out, N, E);
}

// Round 11
// 257.293 us; speedup vs baseline: 2.7308x; 1.1525x over previous
//
#include <hip/hip_runtime.h>

typedef unsigned int u32;
typedef unsigned short u16;
typedef short bf16x8 __attribute__((ext_vector_type(8)));   // 8 bf16 (4 VGPRs)
typedef float f32x4 __attribute__((ext_vector_type(4)));    // MFMA accumulator

#define NCB 256   // blocks for count/place passes (fixed)

__device__ __forceinline__ float bf2f(u16 h) { return __uint_as_float(((u32)h) << 16); }
__device__ __forceinline__ u16 f2bf(float f) {
    u32 u = __float_as_uint(f);
    return (u16)((u + 0x7fffu + ((u >> 16) & 1u)) >> 16);   // RNE
}

// ---------------- diagnostic fallback: ws too small ----------------
__global__ __launch_bounds__(256) void k_sentinel(u16* out, int n) {
    int i = blockIdx.x * 256 + threadIdx.x;
    if (i < n) out[i] = f2bf(-7.0f);
}

// ---------------- dtype detection: flag=0 bf16-packed, flag=1 f32 ----------------
__global__ void k_detect(const u32* x, int* flag) {
    int lane = threadIdx.x;  // 64 threads
    int c = 0;
    for (int j = 0; j < 4; ++j) {
        u32 u = x[lane * 4 + j];
        u32 e = (u >> 7) & 0xffu;
        if ((e >= 0x30u && e <= 0x47u) || ((u & 0x7fffu) == 0u)) ++c;
    }
    for (int d = 32; d; d >>= 1) c += __shfl_down(c, d, 64);
    if (lane == 0) *flag = (c < 128) ? 1 : 0;
}

// ---------------- front: x-convert + param-convert + bucket count (NO deg atomics)
// roles by blockIdx: [0,cvtB) cvt4 | [cvtB,cvtB+134) cvtp | [cvtB+134,+256) count
__global__ __launch_bounds__(256) void k_front(
    const void* x, const int* dstv, const int* flag, int bucketed,
    uint4* X, int* C, int E, int N, int chunk, int cvtB,
    const void* s1l, const void* s1r, const void* shl, const void* shr,
    const void* s2l, const void* s2r, const void* sb1, const void* sbh,
    const void* sb2,
    u32* w1l, u32* w1r, u32* whl, u32* whr, u32* w2l, u32* w2r,
    float* bf1, float* bfh, float* bf2) {
    __shared__ int hist[256];
    int b = blockIdx.x, t = threadIdx.x;
    if (b < cvtB) {
        int i = b * 256 + t;
        if (i >= N * 16) return;
        if (*flag) {
            const float4* s = (const float4*)x;
            float4 a = s[2 * i], c4 = s[2 * i + 1];
            uint4 o;
            o.x = (u32)f2bf(a.x) | ((u32)f2bf(a.y) << 16);
            o.y = (u32)f2bf(a.z) | ((u32)f2bf(a.w) << 16);
            o.z = (u32)f2bf(c4.x) | ((u32)f2bf(c4.y) << 16);
            o.w = (u32)f2bf(c4.z) | ((u32)f2bf(c4.w) << 16);
            X[i] = o;
        } else {
            X[i] = ((const uint4*)x)[i];
        }
    } else if (b < cvtB + 134) {
        int bb = b - cvtB;
        int fl = *flag;
        auto cv = [&](const void* src, u32* dst, int base) {
            int i = base + t;
            if (fl) {
                const float* s = (const float*)src;
                dst[i] = (u32)f2bf(s[2 * i]) | ((u32)f2bf(s[2 * i + 1]) << 16);
            } else {
                dst[i] = ((const u32*)src)[i];
            }
        };
        auto cb = [&](const void* src, float* dst, int i) {
            dst[i] = fl ? ((const float*)src)[i] : bf2f(((const u16*)src)[i]);
        };
        if      (bb <  32) cv(s1l, w1l, bb * 256);
        else if (bb <  64) cv(s1r, w1r, (bb - 32) * 256);
        else if (bb <  96) cv(shl, whl, (bb - 64) * 256);
        else if (bb < 128) cv(shr, whr, (bb - 96) * 256);
        else if (bb < 130) cv(s2l, w2l, (bb - 128) * 256);
        else if (bb < 132) cv(s2r, w2r, (bb - 130) * 256);
        else if (bb == 132) {
            if (t < 128) cb(sb1, bf1, t);
            else         cb(sbh, bfh, t - 128);
        } else {
            if (t < 8) cb(sb2, bf2, t);
        }
    } else if (bucketed) {
        int cb2 = b - cvtB - 134;    // count block 0..255
        hist[t] = 0;
        __syncthreads();
        int e0 = cb2 * chunk;
        int e1 = min(e0 + chunk, E);
        for (int e = e0 + t; e < e1; e += 256) {
            int d = min(max(dstv[e], 0), N - 1);
            atomicAdd(&hist[d >> 8], 1);   // LDS only
        }
        __syncthreads();
        C[cb2 * 256 + t] = hist[t];        // transposed: coalesced write
    }
}

// ---------------- per-bucket: exclusive scan of C over blocks + total -------------
__global__ __launch_bounds__(256) void k_scanT(int* C, int* T) {
    __shared__ int sm[256];
    int bu = blockIdx.x, t = threadIdx.x;
    int v = C[t * 256 + bu];
    sm[t] = v;
    __syncthreads();
    for (int off = 1; off < 256; off <<= 1) {
        int u = (t >= off) ? sm[t - off] : 0;
        __syncthreads();
        sm[t] += u;
        __syncthreads();
    }
    C[t * 256 + bu] = sm[t] - v;       // block-prefix within bucket
    if (t == 255) T[bu] = sm[255];     // bucket total
}

// ---------------- exclusive scan of bucket totals -> bucket bases -----------------
__global__ __launch_bounds__(256) void k_scanB(const int* T, int* B, int nbuk) {
    __shared__ int sm[256];
    int t = threadIdx.x;
    int v = (t < nbuk) ? T[t] : 0;
    sm[t] = v;
    __syncthreads();
    for (int off = 1; off < 256; off <<= 1) {
        int u = (t >= off) ? sm[t - off] : 0;
        __syncthreads();
        sm[t] += u;
        __syncthreads();
    }
    B[t] = sm[t] - v;
}

// ---------------- place edges into bucket-segmented pairs ----------------
__global__ __launch_bounds__(256) void k_place(const int* srcv, const int* dstv,
                                               const int* C, const int* Bb,
                                               u32* pairs, int E, int N, int chunk) {
    __shared__ int base[256], cnt[256];
    int t = threadIdx.x;
    base[t] = Bb[t] + C[blockIdx.x * 256 + t];
    cnt[t] = 0;
    __syncthreads();
    int e0 = blockIdx.x * chunk;
    int e1 = min(e0 + chunk, E);
    for (int e = e0 + t; e < e1; e += 256) {
        int d = min(max(dstv[e], 0), N - 1);
        int s = min(max(srcv[e], 0), N - 1);
        int b = d >> 8;
        int pos = base[b] + atomicAdd(&cnt[b], 1);
        pos = min(max(pos, 0), E - 1);
        pairs[pos] = ((u32)s << 8) | (u32)(d & 255);
    }
}

// ---------------- per-bucket: local degree count + scan -> rowptr; scatter adj ----
// Derives per-node degrees from the bucket's own pairs segment (LDS atomics),
// writes rowptr for its 256 nodes, then scatters adj within the bucket's
// XCD-exclusive window. No global atomics anywhere.
__global__ __launch_bounds__(256) void k_fillb2(const u32* pairs, const int* Bb,
                                                const int* T, int* rowptr,
                                                int* adj, int E, int N, int nbuk) {
    int bu = blockIdx.x;
    int n0 = bu << 8;
    int nn = min(N - n0, 256);
    __shared__ int dcnt[256], sm[256], cur[256];
    int t = threadIdx.x;
    dcnt[t] = 0;
    __syncthreads();
    int s0 = min(max(Bb[bu], 0), E);
    int s1 = min(s0 + max(T[bu], 0), E);
    for (int e = s0 + t; e < s1; e += 256) {
        int ld = (int)(pairs[e] & 255u);
        atomicAdd(&dcnt[min(ld, nn - 1)], 1);
    }
    __syncthreads();
    int v = dcnt[t];
    sm[t] = v;
    __syncthreads();
    for (int off = 1; off < 256; off <<= 1) {
        int u = (t >= off) ? sm[t - off] : 0;
        __syncthreads();
        sm[t] += u;
        __syncthreads();
    }
    int excl = sm[t] - v;
    cur[t] = excl;
    if (t < nn) rowptr[n0 + t] = s0 + excl;
    if (bu == nbuk - 1 && t == 0) rowptr[N] = E;
    __syncthreads();
    for (int e = s0 + t; e < s1; e += 256) {
        u32 pc = pairs[e];
        int ld = min((int)(pc & 255u), nn - 1);
        int src = (int)(pc >> 8);
        int slot = atomicAdd(&cur[ld], 1);
        int idx = min(max(s0 + slot, 0), E - 1);
        adj[idx] = src;
    }
}

// ---------------- fallback CSR for N > 65536 (global atomics path) ----------------
__global__ __launch_bounds__(256) void k_zero(int* deg, int N) {
    int i = blockIdx.x * 256 + threadIdx.x;
    if (i < N) deg[i] = 0;
}
__global__ __launch_bounds__(256) void k_deg(const int* dstv, int* deg, int E, int N) {
    int e = blockIdx.x * 256 + threadIdx.x;
    if (e >= E) return;
    int d = dstv[e]; d = min(max(d, 0), N - 1);
    atomicAdd(&deg[d], 1);
}
__global__ __launch_bounds__(512) void k_scan1(const int* deg, int* r0,
                                               int* bsums, int N) {
    __shared__ int sm[512];
    int i = blockIdx.x * 512 + threadIdx.x;
    int v = (i < N) ? deg[i] : 0;
    sm[threadIdx.x] = v;
    __syncthreads();
    for (int off = 1; off < 512; off <<= 1) {
        int t = (threadIdx.x >= off) ? sm[threadIdx.x - off] : 0;
        __syncthreads();
        sm[threadIdx.x] += t;
        __syncthreads();
    }
    if (i < N) r0[i] = sm[threadIdx.x] - v;
    if (threadIdx.x == 511) bsums[blockIdx.x] = sm[511];
}
__global__ __launch_bounds__(128) void k_scan2f(int* bsums, int nb) {
    __shared__ int sm[128];
    int v = (threadIdx.x < nb) ? bsums[threadIdx.x] : 0;
    sm[threadIdx.x] = v;
    __syncthreads();
    for (int off = 1; off < 128; off <<= 1) {
        int t = (threadIdx.x >= off) ? sm[threadIdx.x - off] : 0;
        __syncthreads();
        sm[threadIdx.x] += t;
        __syncthreads();
    }
    if (threadIdx.x < nb) bsums[threadIdx.x] = sm[threadIdx.x] - v;
}
__global__ __launch_bounds__(512) void k_scan3f(const int* r0, const int* bsums,
                                                int* rowptr, int N, int E) {
    int i = blockIdx.x * 512 + threadIdx.x;
    if (i < N) rowptr[i] = r0[i] + bsums[blockIdx.x];
    if (i == 0) rowptr[N] = E;
}
__global__ __launch_bounds__(256) void k_fill(const int* srcv, const int* dstv,
                                              const int* rowptr, int* deg,
                                              int* adj, int E, int N) {
    int e = blockIdx.x * 256 + threadIdx.x;
    if (e >= E) return;
    int d = dstv[e]; d = min(max(d, 0), N - 1);
    int slot = atomicSub(&deg[d], 1) - 1;
    int idx = rowptr[d] + slot;
    idx = min(max(idx, 0), E - 1);
    adj[idx] = srcv[e];
}

// ---------------- mean aggregation: one wave per node, masked full-ILP -----------
__device__ __forceinline__ void acc8m(uint4 u, float m, float* s) {
    const u32* pu = (const u32*)&u;
#pragma unroll
    for (int t = 0; t < 4; ++t) {
        s[2 * t]     = fmaf(__uint_as_float(pu[t] << 16), m, s[2 * t]);
        s[2 * t + 1] = fmaf(__uint_as_float(pu[t] & 0xffff0000u), m, s[2 * t + 1]);
    }
}

__global__ __launch_bounds__(256) void k_aggregate(const uint4* F, const int* rowptr,
                                                   const int* adj, uint4* A,
                                                   int N, int E) {
    int wid = (int)((blockIdx.x * 256u + threadIdx.x) >> 6);
    int lane = threadIdx.x & 63;
    if (wid >= N) return;
    int beg = rowptr[wid], end = rowptr[wid + 1];
    beg = min(max(beg, 0), E);
    end = min(max(end, beg), E);
    int g = lane >> 4, l = lane & 15;
    float s[8] = {0.f, 0.f, 0.f, 0.f, 0.f, 0.f, 0.f, 0.f};
    for (int j = beg + g; j < end; j += 16) {
        int i1 = j + 4, i2 = j + 8, i3 = j + 12;
        float m1 = (i1 < end) ? 1.f : 0.f;
        float m2 = (i2 < end) ? 1.f : 0.f;
        float m3 = (i3 < end) ? 1.f : 0.f;
        int a0 = min(max(adj[j], 0), N - 1);
        int a1 = min(max(adj[min(i1, end - 1)], 0), N - 1);
        int a2 = min(max(adj[min(i2, end - 1)], 0), N - 1);
        int a3 = min(max(adj[min(i3, end - 1)], 0), N - 1);
        uint4 u0 = F[(size_t)a0 * 16 + l];
        uint4 u1 = F[(size_t)a1 * 16 + l];
        uint4 u2 = F[(size_t)a2 * 16 + l];
        uint4 u3 = F[(size_t)a3 * 16 + l];
        acc8m(u0, 1.f, s);
        acc8m(u1, m1, s);
        acc8m(u2, m2, s);
        acc8m(u3, m3, s);
    }
#pragma unroll
    for (int k = 0; k < 8; ++k) {
        s[k] += __shfl_xor(s[k], 16, 64);
        s[k] += __shfl_xor(s[k], 32, 64);
    }
    if (g == 0) {
        float inv = 1.f / fmaxf((float)(end - beg), 1.f);
        uint4 r; u32* pr = (u32*)&r;
#pragma unroll
        for (int t = 0; t < 4; ++t)
            pr[t] = (u32)f2bf(s[2 * t] * inv) | ((u32)f2bf(s[2 * t + 1] * inv) << 16);
        A[(size_t)wid * 16 + l] = r;
    }
}

// ---------------- layer-1 GEMM: h1 = relu(Agg@Wl^T + b + Xin@Wr^T) ----------------
__global__ __launch_bounds__(256) void k_gemm128(const u16* Agg, const u16* Xin,
                                                 const u32* Wl, const u32* Wr,
                                                 const float* bias, u16* Out, int N) {
    __shared__ __align__(16) u16 Wsh[32768];   // 64 KB -> 2 blocks/CU
    int t = threadIdx.x;
#pragma unroll
    for (int i = 0; i < 16; ++i) {
        int f = i * 256 + t;
        int c = f >> 9, s = (f >> 6) & 7, q = (f >> 4) & 3, n = f & 15;
        int o = c * 16 + n;
        int k = s * 32 + q * 8;
        uint4 v;
        if (k < 128) v = *(const uint4*)(Wl + (size_t)o * 64 + (k >> 1));
        else         v = *(const uint4*)(Wr + (size_t)o * 64 + ((k - 128) >> 1));
        *(uint4*)(Wsh + f * 8) = v;
    }
    __syncthreads();

    int tile = blockIdx.x * 4 + (t >> 6);
    int lane = t & 63;
    int m0 = tile * 16;
    if (m0 >= N) return;
    int mrow = min(m0 + (lane & 15), N - 1);
    int kq = (lane >> 4) * 8;

    bf16x8 afrag[8];
#pragma unroll
    for (int s = 0; s < 8; ++s) {
        int k = s * 32 + kq;
        const u16* p = (k < 128) ? (Agg + (size_t)mrow * 128 + k)
                                 : (Xin + (size_t)mrow * 128 + (k - 128));
        afrag[s] = *(const bf16x8*)p;
    }

    f32x4 acc[8];
#pragma unroll
    for (int c = 0; c < 8; ++c) acc[c] = (f32x4){0.f, 0.f, 0.f, 0.f};

    const u16* lbase = Wsh + (lane >> 4) * 128 + (lane & 15) * 8;
#pragma unroll
    for (int c = 0; c < 8; ++c) {
#pragma unroll
        for (int s = 0; s < 8; ++s) {
            bf16x8 b = *(const bf16x8*)(lbase + (c * 8 + s) * 512);
            acc[c] = __builtin_amdgcn_mfma_f32_16x16x32_bf16(afrag[s], b, acc[c], 0, 0, 0);
        }
    }

#pragma unroll
    for (int c = 0; c < 8; ++c) {
        int o = c * 16 + (lane & 15);
        float bv = bias[o];
#pragma unroll
        for (int r = 0; r < 4; ++r) {
            int m = m0 + (lane >> 4) * 4 + r;
            float v = acc[c][r] + bv;
            v = fmaxf(v, 0.f);   // relu
            if (m < N) Out[(size_t)m * 128 + o] = f2bf(v);
        }
    }
}

// ---------------- layer-2 GEMM + elu + fused layer-3 head ------------------------
__global__ __launch_bounds__(256) void k_gemm2(const u16* Agg, const u16* Xin,
                                               const u32* Wl, const u32* Wr,
                                               const float* bias,
                                               const u32* W2l, const u32* W2r,
                                               const float* b2,
                                               float* Y, float* R, int N) {
    __shared__ __align__(16) u16 Wsh[32768];   // 64 KB
    __shared__ float W2sh[2048];               // +8 KB: W2l,W2r as f32
    int t = threadIdx.x;
#pragma unroll
    for (int i = 0; i < 16; ++i) {
        int f = i * 256 + t;
        int c = f >> 9, s = (f >> 6) & 7, q = (f >> 4) & 3, n = f & 15;
        int o = c * 16 + n;
        int k = s * 32 + q * 8;
        uint4 v;
        if (k < 128) v = *(const uint4*)(Wl + (size_t)o * 64 + (k >> 1));
        else         v = *(const uint4*)(Wr + (size_t)o * 64 + ((k - 128) >> 1));
        *(uint4*)(Wsh + f * 8) = v;
    }
#pragma unroll
    for (int i = t; i < 512; i += 256) {
        u32 wa = W2l[i], wb = W2r[i];
        W2sh[2 * i]            = bf2f((u16)(wa & 0xffffu));
        W2sh[2 * i + 1]        = bf2f((u16)(wa >> 16));
        W2sh[1024 + 2 * i]     = bf2f((u16)(wb & 0xffffu));
        W2sh[1024 + 2 * i + 1] = bf2f((u16)(wb >> 16));
    }
    __syncthreads();

    int tile = blockIdx.x * 4 + (t >> 6);
    int lane = t & 63;
    int m0 = tile * 16;
    if (m0 >= N) return;
    int mrow = min(m0 + (lane & 15), N - 1);
    int kq = (lane >> 4) * 8;

    bf16x8 afrag[8];
#pragma unroll
    for (int s = 0; s < 8; ++s) {
        int k = s * 32 + kq;
        const u16* p = (k < 128) ? (Agg + (size_t)mrow * 128 + k)
                                 : (Xin + (size_t)mrow * 128 + (k - 128));
        afrag[s] = *(const bf16x8*)p;
    }

    f32x4 acc[8];
#pragma unroll
    for (int c = 0; c < 8; ++c) acc[c] = (f32x4){0.f, 0.f, 0.f, 0.f};

    const u16* lbase = Wsh + (lane >> 4) * 128 + (lane & 15) * 8;
#pragma unroll
    for (int c = 0; c < 8; ++c) {
#pragma unroll
        for (int s = 0; s < 8; ++s) {
            bf16x8 b = *(const bf16x8*)(lbase + (c * 8 + s) * 512);
            acc[c] = __builtin_amdgcn_mfma_f32_16x16x32_bf16(afrag[s], b, acc[c], 0, 0, 0);
        }
    }

    int quad = lane >> 4, k15 = lane & 15;
#pragma unroll
    for (int c = 0; c < 8; ++c) {
        float bv = bias[c * 16 + k15];
#pragma unroll
        for (int r = 0; r < 4; ++r) {
            float v = acc[c][r] + bv;
            acc[c][r] = (v > 0.f) ? v : expm1f(v);   // elu
        }
    }
#pragma unroll
    for (int j = 0; j < 8; ++j) {
        float py[4] = {0.f, 0.f, 0.f, 0.f};
        float pr[4] = {0.f, 0.f, 0.f, 0.f};
#pragma unroll
        for (int c = 0; c < 8; ++c) {
            float w1 = W2sh[j * 128 + c * 16 + k15];
            float w2 = W2sh[1024 + j * 128 + c * 16 + k15];
#pragma unroll
            for (int r = 0; r < 4; ++r) {
                py[r] = fmaf(acc[c][r], w1, py[r]);
                pr[r] = fmaf(acc[c][r], w2, pr[r]);
            }
        }
#pragma unroll
        for (int r = 0; r < 4; ++r) {
#pragma unroll
            for (int d = 1; d < 16; d <<= 1) {
                py[r] += __shfl_xor(py[r], d, 64);
                pr[r] += __shfl_xor(pr[r], d, 64);
            }
            int m = m0 + quad * 4 + r;
            if (k15 == j && m < N) {
                Y[(size_t)m * 8 + j] = py[r];
                R[(size_t)m * 8 + j] = pr[r] + b2[j];
            }
        }
    }
}

// ---------------- final: mean-aggregate Y + R + log_softmax ----------------------
__global__ __launch_bounds__(256) void k_agg8sm(const float* Y, const float* R,
                                                const int* rowptr, const int* adj,
                                                const int* flag, void* Out,
                                                int N, int E) {
    int t = blockIdx.x * 256 + threadIdx.x;
    int n = t >> 3;
    int o = t & 7;
    if (n >= N) return;
    int beg = rowptr[n], end = rowptr[n + 1];
    beg = min(max(beg, 0), E);
    end = min(max(end, beg), E);
    float s = 0.f;
    int j = beg;
    for (; j + 1 < end; j += 2) {
        int a0 = min(max(adj[j], 0), N - 1);
        int a1 = min(max(adj[j + 1], 0), N - 1);
        s += Y[(size_t)a0 * 8 + o];
        s += Y[(size_t)a1 * 8 + o];
    }
    if (j < end) {
        int a0 = min(max(adj[j], 0), N - 1);
        s += Y[(size_t)a0 * 8 + o];
    }
    float acc = s / fmaxf((float)(end - beg), 1.f) + R[(size_t)n * 8 + o];
    float mx = acc;
#pragma unroll
    for (int d = 1; d < 8; d <<= 1) mx = fmaxf(mx, __shfl_xor(mx, d, 64));
    float ex = expf(acc - mx), se = ex;
#pragma unroll
    for (int d = 1; d < 8; d <<= 1) se += __shfl_xor(se, d, 64);
    float v = acc - mx - logf(se);
    if (*flag) ((float*)Out)[(size_t)n * 8 + o] = v;
    else       ((u16*)Out)[(size_t)n * 8 + o] = f2bf(v);
}

// ---------------- launch ----------------
extern "C" void kernel_launch(void* const* d_in, const int* in_sizes, int n_in,
                              void* d_out, int out_size, void* d_ws, size_t ws_size,
                              hipStream_t stream) {
    const void* x   = d_in[0];
    const int* ei   = (const int*)d_in[1];
    const int N = in_sizes[0] / 128;
    const int E = in_sizes[1] / 2;
    const int* srcv = ei;
    const int* dstv = ei + E;
    const int NBUK = (N + 255) >> 8;         // buckets of 256 nodes
    const int bucketed = (NBUK <= 256) ? 1 : 0;
    const int chunk = (E + NCB - 1) / NCB;
    const int cvtB = (N * 16 + 255) / 256;
    const int nbA = (N + 511) / 512;

    auto rnd = [](size_t b) { return (b + 255) & ~(size_t)255; };
    size_t need = rnd(256)                    // flag
                + rnd((size_t)N * 4)          // deg (fallback)
                + rnd((size_t)N * 4)          // r0 (fallback)
                + rnd((size_t)(N + 1) * 4)    // rowptr
                + rnd(4096)                   // bsums (fallback)
                + rnd(256 * NCB * 4)          // C matrix
                + rnd(1024) + rnd(1024)       // T, B
                + rnd((size_t)E * 4)          // adj
                + 2 * rnd((size_t)N * 256)    // X, A
                + 2 * rnd((size_t)N * 32)     // Y, R
                + 4 * rnd(32768) + 2 * rnd(2048) + 2 * rnd(512) + rnd(64);
    if (ws_size < need) {
        k_sentinel<<<(out_size + 255) / 256, 256, 0, stream>>>((u16*)d_out, out_size);
        return;
    }

    char* p = (char*)d_ws;
    auto carve = [&](size_t bytes) { char* r = p; p += (bytes + 255) & ~(size_t)255; return r; };
    int* flag   = (int*)carve(256);
    int* deg    = (int*)carve((size_t)N * 4);
    int* r0     = (int*)carve((size_t)N * 4);
    int* rowptr = (int*)carve((size_t)(N + 1) * 4);
    int* bsums  = (int*)carve(4096);
    int* C      = (int*)carve(256 * NCB * 4);
    int* T      = (int*)carve(1024);
    int* B      = (int*)carve(1024);
    int* adj    = (int*)carve((size_t)E * 4);
    u32* X      = (u32*)carve((size_t)N * 256);   // [N,128] packed bf16
    u32* A      = (u32*)carve((size_t)N * 256);   // agg buffer
    float* Y    = (float*)carve((size_t)N * 32);  // [N,8] f32
    float* R    = (float*)carve((size_t)N * 32);
    u32* w1l = (u32*)carve(32768); u32* w1r = (u32*)carve(32768);
    u32* whl = (u32*)carve(32768); u32* whr = (u32*)carve(32768);
    u32* w2l = (u32*)carve(2048);  u32* w2r = (u32*)carve(2048);
    float* bf1 = (float*)carve(512); float* bfh = (float*)carve(512);
    float* bf2 = (float*)carve(64);
    u32* pairs = A;                  // consumed by k_fillb2 before first aggregate
    (void)n_in;

    // 1: dtype detect
    k_detect<<<1, 64, 0, stream>>>((const u32*)x, flag);
    // 2: convert x + params + bucket count (LDS-only atomics)
    k_front<<<cvtB + 134 + (bucketed ? 256 : 0), 256, 0, stream>>>(
        x, dstv, flag, bucketed, (uint4*)X, C, E, N, chunk, cvtB,
        d_in[3], d_in[5], d_in[6], d_in[8], d_in[9], d_in[11],
        d_in[4], d_in[7], d_in[10],
        w1l, w1r, whl, whr, w2l, w2r, bf1, bfh, bf2);
    if (bucketed) {
        // 3-4: bucket scans (tiny)
        k_scanT<<<NBUK, 256, 0, stream>>>(C, T);
        k_scanB<<<1, 256, 0, stream>>>(T, B, NBUK);
        // 5: bucket-segmented edge placement
        k_place<<<NCB, 256, 0, stream>>>(srcv, dstv, C, B, pairs, E, N, chunk);
        // 6: local degree count + rowptr + adj scatter (no global atomics)
        k_fillb2<<<NBUK, 256, 0, stream>>>(pairs, B, T, rowptr, adj, E, N, NBUK);
    } else {
        k_zero<<<(N + 255) / 256, 256, 0, stream>>>(deg, N);
        k_deg<<<(E + 255) / 256, 256, 0, stream>>>(dstv, deg, E, N);
        k_scan1<<<nbA, 512, 0, stream>>>(deg, r0, bsums, N);
        k_scan2f<<<1, 128, 0, stream>>>(bsums, nbA);
        k_scan3f<<<nbA, 512, 0, stream>>>(r0, bsums, rowptr, N, E);
        k_fill<<<(E + 255) / 256, 256, 0, stream>>>(srcv, dstv, rowptr, deg, adj, E, N);
    }

    int aggBlocks = (int)(((size_t)N * 64 + 255) / 256);
    int gemmBlocks = ((N + 15) / 16 + 3) / 4;
    int perNode8 = (int)(((size_t)N * 8 + 255) / 256);

    // 7-8: L1  A=mean(X); h1=relu(A@W1l^T+b1+X@W1r^T) -> X (own-rows aliasing)
    k_aggregate<<<aggBlocks, 256, 0, stream>>>((const uint4*)X, rowptr, adj, (uint4*)A, N, E);
    k_gemm128<<<gemmBlocks, 256, 0, stream>>>((const u16*)A, (const u16*)X, w1l, w1r, bf1, (u16*)X, N);
    // 9-10: L2 A=mean(h1); fused gemm2+elu+head -> Y,R (h2 never materialized)
    k_aggregate<<<aggBlocks, 256, 0, stream>>>((const uint4*)X, rowptr, adj, (uint4*)A, N, E);
    k_gemm2<<<gemmBlocks, 256, 0, stream>>>((const u16*)A, (const u16*)X, whl, whr, bfh,
                                            w2l, w2r, bf2, Y, R, N);
    // 11: out = log_softmax(mean_agg(Y) + R)
    k_agg8sm<<<perNode8, 256, 0, stream>>>(Y, R, rowptr, adj, flag, d_out, N, E);
}